// Round 14
// baseline (274.527 us; speedup 1.0000x reference)
//
#include <hip/hip_runtime.h>
#include <stdint.h>

typedef unsigned short u16;
typedef unsigned int u32;
typedef unsigned long long u64;
typedef __attribute__((ext_vector_type(8))) __bf16 bf16x8;
typedef __attribute__((ext_vector_type(8))) u16 u16x8;
typedef __attribute__((ext_vector_type(4))) float f32x4;

#define DEVI __device__ __forceinline__

DEVI u16 f2bf(float f) {                    // fp32 -> bf16 RNE
  u32 u = __float_as_uint(f);
  u += 0x7FFFu + ((u >> 16) & 1u);
  return (u16)(u >> 16);
}
DEVI float bf2f(u16 h) { return __uint_as_float(((u32)h) << 16); }
DEVI u16 mono(u16 b) {                      // order-isomorphic bf16 -> u16
  return (b & 0x8000u) ? (u16)~b : (u16)(b | 0x8000u);
}
DEVI u16 unmono(u16 t) {
  return (t & 0x8000u) ? (u16)(t ^ 0x8000u) : (u16)(~t);
}

DEVI void glds16(const void* g, void* l) {  // 16B-per-lane global->LDS DMA
  __builtin_amdgcn_global_load_lds((const __attribute__((address_space(1))) void*)g,
                                   (__attribute__((address_space(3))) void*)l, 16, 0, 0);
}

// ---------------- prep: pack (x,y,z,||x||^2) per point + zero gsum ----------------
__global__ void k_pack_coords(const float* __restrict__ x, float4* __restrict__ c4,
                              float* __restrict__ gsum) {
  int g = blockIdx.x * 256 + threadIdx.x;          // < 16384
  if (g < 1792) gsum[g] = 0.f;
  float x0 = x[g*3], x1 = x[g*3+1], x2 = x[g*3+2];
  float n = __fadd_rn(__fadd_rn(__fmul_rn(x0,x0), __fmul_rn(x1,x1)), __fmul_rn(x2,x2));
  c4[g] = make_float4(x0, x1, x2, n);
}

// ---------------- prep: all MFMA weights -> bf16 (a/b stacked) ----------------
__global__ void k_pack_w(const float* __restrict__ w2a, const float* __restrict__ w2b,
                         const float* __restrict__ w3a, const float* __restrict__ w3b,
                         const float* __restrict__ w4a, const float* __restrict__ w4b,
                         const float* __restrict__ w51, const float* __restrict__ w52,
                         u16* __restrict__ wbf) {
  int g = blockIdx.x * 256 + threadIdx.x;          // < 1,138,688 exact
  const float* s; int off;
  if      (g <    4096) { s = w2a; off = g; }
  else if (g <    8192) { s = w2b; off = g - 4096; }
  else if (g <   16384) { s = w3a; off = g - 8192; }
  else if (g <   24576) { s = w3b; off = g - 16384; }
  else if (g <   57344) { s = w4a; off = g - 24576; }
  else if (g <   90112) { s = w4b; off = g - 57344; }
  else if (g <  614400) { s = w51; off = g - 90112; }
  else                  { s = w52; off = g - 614400; }
  wbf[g] = f2bf(s[off]);
}

// ---------------- knn: per-row top-80 (R5 structure; 64-VGPR tier forced) ----------------
__global__ __launch_bounds__(256, 8) void k_knn(const float4* __restrict__ c4, int* __restrict__ idxp) {
  __shared__ u64 cand[4][128];
  const int wid = threadIdx.x >> 6;
  const int lane = threadIdx.x & 63;
  const int batch = blockIdx.x & 7;
  const int qib = (blockIdx.x >> 3) * 4 + wid;      // query within batch
  const int blk = (batch << 11) + qib;
  const float4* cb = c4 + (batch << 11);
  const float4 q = cb[qib];

  u32 key[32];
  #pragma unroll
  for (int s = 0; s < 32; ++s) {
    float4 c = cb[s*64 + lane];
    float inner = __fadd_rn(__fadd_rn(__fmul_rn(q.x,c.x), __fmul_rn(q.y,c.y)), __fmul_rn(q.z,c.z));
    float pd = __fsub_rn(__fsub_rn(__fmul_rn(2.0f, inner), q.w), c.w);
    u32 bits = __float_as_uint(pd);
    key[s] = (bits & 0x80000000u) ? ~bits : (bits | 0x80000000u);
  }

  u32 T = 0;
  for (int bit = 30; bit >= 0; --bit) {
    u32 Tc = T | (1u << bit);
    int c = 0;
    #pragma unroll
    for (int s = 0; s < 32; ++s)
      c += __popcll(__ballot(key[s] >= Tc));
    if (c >= 80) { T = Tc; if (c <= 128) break; }
  }

  cand[wid][lane] = 0ull;
  cand[wid][lane + 64] = 0ull;
  asm volatile("s_waitcnt lgkmcnt(0)" ::: "memory");

  const u64 below = (lane == 0) ? 0ull : (~0ull >> (64 - lane));
  int base = 0;
  #pragma unroll
  for (int s = 0; s < 32; ++s) {
    u64 msk = __ballot(key[s] >= T);
    if (key[s] >= T) {
      int pos = base + (int)__popcll(msk & below);
      if (pos < 128)
        cand[wid][pos] = (((u64)key[s]) << 32) | (u32)(2047 - (s*64 + lane));
    }
    base += (int)__popcll(msk);
  }
  asm volatile("s_waitcnt lgkmcnt(0)" ::: "memory");

  u64 v0 = cand[wid][lane];
  u64 v1 = cand[wid][lane + 64];
  #pragma unroll
  for (int k2 = 2; k2 <= 128; k2 <<= 1) {
    #pragma unroll
    for (int j = k2 >> 1; j > 0; j >>= 1) {
      if (j == 64) {                                // cross-slot, in-lane
        u64 mx = v0 > v1 ? v0 : v1;
        u64 mn = v0 > v1 ? v1 : v0;
        v0 = mx; v1 = mn;
      } else {
        u64 p0 = __shfl_xor(v0, j, 64);
        u64 p1 = __shfl_xor(v1, j, 64);
        bool lowlane = ((lane & j) == 0);
        bool d0 = ((lane & k2) == 0);
        bool d1 = (((lane + 64) & k2) == 0);
        bool wm0 = (d0 == lowlane);
        bool wm1 = (d1 == lowlane);
        u64 mx0 = v0 > p0 ? v0 : p0, mn0 = v0 > p0 ? p0 : v0;
        u64 mx1 = v1 > p1 ? v1 : p1, mn1 = v1 > p1 ? p1 : v1;
        v0 = wm0 ? mx0 : mn0;
        v1 = wm1 ? mx1 : mn1;
      }
    }
  }

  idxp[(size_t)blk*80 + lane] = 2047 - (int)(u32)v0;
  if (lane < 16) idxp[(size_t)blk*80 + 64 + lane] = 2047 - (int)(u32)v1;
}

// ---------------- layer 1 conv (K=3, fp32) + fused stats, store mono' ----------------
__global__ __launch_bounds__(256) void k_conv1(const float* __restrict__ x,
    const float* __restrict__ w1a, const float* __restrict__ w1b,
    const float* __restrict__ g1a, const float* __restrict__ g1b,
    u16* __restrict__ out, float* __restrict__ gsum) {
  __shared__ float xs[384];
  __shared__ float colsum[128], colss[128];
  const int tid = threadIdx.x;
  const int P0 = blockIdx.x * 128;
  for (int i = tid; i < 384; i += 256) xs[i] = x[P0*3 + i];
  if (tid < 128) { colsum[tid] = 0.f; colss[tid] = 0.f; }
  __syncthreads();

  const int c = tid & 127;
  const int half = tid >> 7;
  const float* w = (c < 64) ? (w1a + 3*c) : (w1b + 3*(c-64));
  float wx = w[0], wy = w[1], wz = w[2];
  float gam = (c < 64) ? g1a[c] : g1b[c-64];
  u16 flip = (gam < 0.f) ? (u16)0xFFFF : (u16)0;

  float s = 0.f, ss = 0.f;
  #pragma unroll 4
  for (int p_ = 0; p_ < 64; ++p_) {
    int p = (half << 6) + p_;
    float h = wx*xs[p*3] + wy*xs[p*3+1] + wz*xs[p*3+2];
    s += h; ss += h*h;
    out[(size_t)(P0 + p)*128 + c] = (u16)(mono(f2bf(h)) ^ flip);
  }
  atomicAdd(&colsum[c], s);
  atomicAdd(&colss[c], ss);
  __syncthreads();
  if (tid < 16) {
    float gs = 0.f, gss = 0.f;
    #pragma unroll
    for (int q = 0; q < 8; ++q) { gs += colsum[tid*8+q]; gss += colss[tid*8+q]; }
    int b = blockIdx.x >> 4;
    atomicAdd(&gsum[(b*16 + tid)*2],   gs);
    atomicAdd(&gsum[(b*16 + tid)*2+1], gss);
  }
}

// ---------------- fused gather-max + GroupNorm + LeakyReLU + add-fb ----------------
__global__ __launch_bounds__(256) void k_gather(const u16* __restrict__ conv, int Ctot, int Ca,
    int CgShift, int NG, const float* __restrict__ gsum,
    const float* __restrict__ ga, const float* __restrict__ ba,
    const float* __restrict__ gb, const float* __restrict__ bb,
    const int* __restrict__ idxp, int k,
    u16* __restrict__ xcat, int outOff, int lppShift) {
  const int batch = blockIdx.x & 7;
  const int blkin = blockIdx.x >> 3;
  const int lgid = blkin * 256 + threadIdx.x;
  const int p_in = lgid >> lppShift;
  const int c8 = (lgid & ((1 << lppShift) - 1)) * 8;
  const int p = (batch << 11) + p_in;
  const int* irow = idxp + (size_t)p * 80;
  const u16* cb = conv + ((size_t)(batch << 11)) * Ctot + c8;

  const int gia = c8 >> CgShift;
  const int gib = (Ca + c8) >> CgShift;
  const float cnt = (float)(2048 << CgShift);
  float2 sa = *(const float2*)(gsum + (size_t)(batch*NG + gia)*2);
  float2 sb = *(const float2*)(gsum + (size_t)(batch*NG + gib)*2);
  float meanA = sa.x / cnt, rstdA = rsqrtf(sa.y / cnt - meanA*meanA + 1e-5f);
  float meanB = sb.x / cnt, rstdB = rsqrtf(sb.y / cnt - meanB*meanB + 1e-5f);

  float gav[8], bav[8], gbv[8], bbv[8];
  *(float4*)&gav[0] = *(const float4*)(ga + c8); *(float4*)&gav[4] = *(const float4*)(ga + c8 + 4);
  *(float4*)&bav[0] = *(const float4*)(ba + c8); *(float4*)&bav[4] = *(const float4*)(ba + c8 + 4);
  *(float4*)&gbv[0] = *(const float4*)(gb + c8); *(float4*)&gbv[4] = *(const float4*)(gb + c8 + 4);
  *(float4*)&bbv[0] = *(const float4*)(bb + c8); *(float4*)&bbv[4] = *(const float4*)(bb + c8 + 4);

  u16x8 fbv = *(const u16x8*)(conv + (size_t)p * Ctot + Ca + c8);

  u16x8 m8 = (u16x8)(u16)0;
  for (int j0 = 0; j0 < k; j0 += 4) {
    int4 mi4 = *(const int4*)(irow + j0);
    int mis[4] = {mi4.x, mi4.y, mi4.z, mi4.w};
    u16x8 rows[4];
    #pragma unroll
    for (int u = 0; u < 4; ++u)
      rows[u] = *(const u16x8*)(cb + (size_t)mis[u] * Ctot);
    #pragma unroll
    for (int u = 0; u < 4; ++u)
      m8 = __builtin_elementwise_max(m8, rows[u]);   // v_pk_max_u16
  }

  u16 ov[8];
  #pragma unroll
  for (int q = 0; q < 8; ++q) {
    u16 fA = (gav[q] < 0.f) ? (u16)0xFFFF : (u16)0;
    u16 fB = (gbv[q] < 0.f) ? (u16)0xFFFF : (u16)0;
    float xa = bf2f(unmono((u16)((u16)m8[q] ^ fA)));
    float ha = (xa - meanA) * rstdA * gav[q] + bav[q];
    ha = ha > 0.f ? ha : 0.2f * ha;
    float xb = bf2f(unmono((u16)((u16)fbv[q] ^ fB)));
    float hb = (xb - meanB) * rstdB * gbv[q] + bbv[q];
    hb = hb > 0.f ? hb : 0.2f * hb;
    ov[q] = f2bf(ha + hb);
  }
  *(u16x8*)(xcat + (size_t)p * 512 + outOff + c8) = *(u16x8*)ov;
}

// ---------------- scale/bias tables for layer 5_1 GN (replaces apply51 pass) ----------------
__global__ void k_sb51(const float* __restrict__ gsum, const float* __restrict__ g,
                       const float* __restrict__ b, float* __restrict__ sc,
                       float* __restrict__ bi) {
  int i = blockIdx.x * 256 + threadIdx.x;            // < 8192 (8 batches x 1024 ch)
  int bb = i >> 10, c = i & 1023;
  int grp = c >> 6;
  float2 s = *(const float2*)(gsum + (size_t)(bb*16 + grp)*2);
  float mean = s.x / 131072.f;
  float rstd = rsqrtf(s.y / 131072.f - mean*mean + 1e-5f);
  float A = rstd * g[c];
  sc[i] = A;
  bi[i] = b[c] - mean * A;
}

// ---------------- GN apply + LeakyReLU from fused sums (layer 5_2, f32) ----------------
__global__ __launch_bounds__(256) void k_apply52(float* __restrict__ act,
    const float* __restrict__ gsum, const float* __restrict__ g, const float* __restrict__ b) {
  int gid = blockIdx.x * 256 + threadIdx.x;
  size_t e = (size_t)gid * 4;
  int row = (int)(e >> 9);
  int c = (int)e & 511;
  int grp = c >> 5;
  float2 s = *(const float2*)(gsum + (size_t)((row >> 11)*16 + grp)*2);
  const float cnt = 65536.f;
  float mean = s.x / cnt, rstd = rsqrtf(s.y / cnt - mean*mean + 1e-5f);
  float4 v = *(const float4*)(act + e);
  float h[4] = {v.x, v.y, v.z, v.w};
  #pragma unroll
  for (int q = 0; q < 4; ++q) {
    float o = (h[q] - mean) * rstd * g[c+q] + b[c+q];
    h[q] = o > 0.f ? o : 0.2f * o;
  }
  *(float4*)(act + e) = make_float4(h[0], h[1], h[2], h[3]);
}

// ---------------- bf16 MFMA GEMM + fused GN stats (+ mono' store / A-transform) ----------------
// 64x128 tile (M-halved): 2x blocks per gemm, ~6 blocks/CU (25.5KB LDS, <=85 VGPR)
// -> more resident blocks to hide the per-iteration vmcnt drain; smaller tail;
// small gemms (L2/L3) now cover the full 256-CU chip.
template<int OUTF32, int MONO, int TRANSA>
__global__ __launch_bounds__(256, 6) void k_gemm(const u16* __restrict__ A, int lda,
    const u16* __restrict__ Bw, int K, void* __restrict__ outp, int ldc,
    int CgShift, int NG, float* __restrict__ gsum,
    const float* __restrict__ ga, const float* __restrict__ gb, int Ca,
    const float* __restrict__ scA, const float* __restrict__ biA) {
  constexpr int BK = 64;
  __shared__ __align__(16) u16 As[64 * BK];         // 8 KB
  __shared__ __align__(16) u16 Bs[128 * BK];        // 16 KB
  __shared__ float colsum[128], colss[128];
  const int tid = threadIdx.x;
  const int wid = tid >> 6, lane = tid & 63;
  const int tileM = blockIdx.x * 64, tileN = blockIdx.y * 128;
  const int wn = wid;                               // 4 waves: cols wn*32..wn*32+31
  const int lr = lane & 15, lk = (lane >> 4) * 8;
  const float* scb = TRANSA ? (scA + (size_t)(tileM >> 11) * 1024) : nullptr;
  const float* bib = TRANSA ? (biA + (size_t)(tileM >> 11) * 1024) : nullptr;

  f32x4 acc[4][2] = {};
  for (int k0 = 0; k0 < K; k0 += BK) {
    __syncthreads();
    // A tile: 64 x 64 u16 = 512 chunks of 16B; 2 per thread
    #pragma unroll
    for (int i = 0; i < 2; ++i) {
      int flat = i * 256 + tid;
      int row = flat >> 3, ck = flat & 7;
      if (TRANSA) {
        int cbase = k0 + ck * 8;
        uint4 v = *(const uint4*)(A + (size_t)(tileM + row) * lda + cbase);
        float4 s0 = *(const float4*)(scb + cbase);
        float4 s1 = *(const float4*)(scb + cbase + 4);
        float4 b0 = *(const float4*)(bib + cbase);
        float4 b1 = *(const float4*)(bib + cbase + 4);
        float sc8[8] = {s0.x,s0.y,s0.z,s0.w,s1.x,s1.y,s1.z,s1.w};
        float bi8[8] = {b0.x,b0.y,b0.z,b0.w,b1.x,b1.y,b1.z,b1.w};
        u32 vv[4] = {v.x, v.y, v.z, v.w};
        u32 ov[4];
        #pragma unroll
        for (int q2 = 0; q2 < 4; ++q2) {
          float x0 = bf2f((u16)(vv[q2] & 0xFFFF));
          float x1 = bf2f((u16)(vv[q2] >> 16));
          float o0 = x0 * sc8[q2*2]   + bi8[q2*2];
          float o1 = x1 * sc8[q2*2+1] + bi8[q2*2+1];
          o0 = o0 > 0.f ? o0 : 0.2f * o0;
          o1 = o1 > 0.f ? o1 : 0.2f * o1;
          ov[q2] = (u32)f2bf(o0) | (((u32)f2bf(o1)) << 16);
        }
        *(uint4*)((char*)As + flat * 16) = make_uint4(ov[0], ov[1], ov[2], ov[3]);
      } else {
        glds16(A + (size_t)(tileM + row) * lda + (k0 + ck * 8), (char*)As + flat * 16);
      }
    }
    // B tile: 128 x 64 u16 = 1024 chunks; 4 per thread
    #pragma unroll
    for (int i = 0; i < 4; ++i) {
      int flat = i * 256 + tid;
      int row = flat >> 3, ck = flat & 7;
      glds16(Bw + (size_t)(tileN + row) * K + (k0 + ck * 8), (char*)Bs + flat * 16);
    }
    __syncthreads();
    #pragma unroll
    for (int ks = 0; ks < 2; ++ks) {
      bf16x8 af[4], bfr[2];
      #pragma unroll
      for (int i = 0; i < 4; ++i)
        af[i] = *(const bf16x8*)&As[(i*16 + lr) * BK + ks*32 + lk];
      #pragma unroll
      for (int j = 0; j < 2; ++j)
        bfr[j] = *(const bf16x8*)&Bs[(wn*32 + j*16 + lr) * BK + ks*32 + lk];
      #pragma unroll
      for (int i = 0; i < 4; ++i)
        #pragma unroll
        for (int j = 0; j < 2; ++j)
          acc[i][j] = __builtin_amdgcn_mfma_f32_16x16x32_bf16(af[i], bfr[j], acc[i][j], 0, 0, 0);
    }
  }

  const int orow0 = tileM + ((lane >> 4) * 4);
  const int ocol0 = tileN + wn*32 + lr;

  u16 flip[2] = {0,0};
  if (MONO) {
    #pragma unroll
    for (int j = 0; j < 2; ++j) {
      int colg = ocol0 + j*16;
      float gm = (colg < Ca) ? ga[colg] : gb[colg - Ca];
      flip[j] = (gm < 0.f) ? (u16)0xFFFF : (u16)0;
    }
  }

  float csum[2] = {0.f,0.f}, css[2] = {0.f,0.f};
  #pragma unroll
  for (int i = 0; i < 4; ++i)
    #pragma unroll
    for (int j = 0; j < 2; ++j)
      #pragma unroll
      for (int r = 0; r < 4; ++r) {
        int row = orow0 + i*16 + r;
        int col = ocol0 + j*16;
        float v = acc[i][j][r];
        csum[j] += v; css[j] += v*v;
        if (OUTF32) ((float*)outp)[(size_t)row * ldc + col] = v;
        else {
          u16 st = f2bf(v);
          if (MONO) st = (u16)(mono(st) ^ flip[j]);
          ((u16*)outp)[(size_t)row * ldc + col] = st;
        }
      }

  #pragma unroll
  for (int mask = 16; mask <= 32; mask <<= 1)
    #pragma unroll
    for (int j = 0; j < 2; ++j) {
      csum[j] += __shfl_xor(csum[j], mask, 64);
      css[j]  += __shfl_xor(css[j],  mask, 64);
    }
  if (tid < 128) { colsum[tid] = 0.f; colss[tid] = 0.f; }
  __syncthreads();
  if ((lane >> 4) == 0) {
    #pragma unroll
    for (int j = 0; j < 2; ++j) {
      int col = wn*32 + j*16 + lr;
      atomicAdd(&colsum[col], csum[j]);
      atomicAdd(&colss[col],  css[j]);
    }
  }
  __syncthreads();
  const int NGtile = 128 >> CgShift;
  if (tid < NGtile) {
    float s = 0.f, ss = 0.f;
    const int Cg = 1 << CgShift;
    for (int c0 = tid << CgShift; c0 < (tid << CgShift) + Cg; ++c0) { s += colsum[c0]; ss += colss[c0]; }
    int b = tileM >> 11;
    int gidx = (tileN >> CgShift) + tid;
    atomicAdd(&gsum[(size_t)(b*NG + gidx)*2],   s);
    atomicAdd(&gsum[(size_t)(b*NG + gidx)*2+1], ss);
  }
}

// ---------------- launch ----------------
extern "C" void kernel_launch(void* const* d_in, const int* in_sizes, int n_in,
                              void* d_out, int out_size, void* d_ws, size_t ws_size,
                              hipStream_t stream) {
  const float* x   = (const float*)d_in[0];
  const float* w1a = (const float*)d_in[1];
  const float* g1a = (const float*)d_in[2];
  const float* b1a = (const float*)d_in[3];
  const float* w1b = (const float*)d_in[4];
  const float* g1b = (const float*)d_in[5];
  const float* b1b = (const float*)d_in[6];
  const float* w2a = (const float*)d_in[7];
  const float* g2a = (const float*)d_in[8];
  const float* b2a = (const float*)d_in[9];
  const float* w2b = (const float*)d_in[10];
  const float* g2b = (const float*)d_in[11];
  const float* b2b = (const float*)d_in[12];
  const float* w3a = (const float*)d_in[13];
  const float* g3a = (const float*)d_in[14];
  const float* b3a = (const float*)d_in[15];
  const float* w3b = (const float*)d_in[16];
  const float* g3b = (const float*)d_in[17];
  const float* b3b = (const float*)d_in[18];
  const float* w4a = (const float*)d_in[19];
  const float* g4a = (const float*)d_in[20];
  const float* b4a = (const float*)d_in[21];
  const float* w4b = (const float*)d_in[22];
  const float* g4b = (const float*)d_in[23];
  const float* b4b = (const float*)d_in[24];
  const float* w51 = (const float*)d_in[25];
  const float* g51 = (const float*)d_in[26];
  const float* b51 = (const float*)d_in[27];
  const float* w52 = (const float*)d_in[28];
  const float* g52 = (const float*)d_in[29];
  const float* b52 = (const float*)d_in[30];

  char* ws = (char*)d_ws;
  int*    idxp   = (int*)   (ws + 0);               // 5,242,880
  float4* c4     = (float4*)(ws + 5242880);         // 262,144
  u16*    wbf    = (u16*)   (ws + 5505024);         // 2,277,376
  float*  gsum   = (float*) (ws + 7782400);         // 8,192
  u16*    convAB = (u16*)   (ws + 7790592);         // 16,777,216
  u16*    h1     = (u16*)   (ws + 24567808);        // 33,554,432
  u16*    xcat   = (u16*)   (ws + 58122240);        // 16,777,216
  // sc51/bi51 alias the convAB region (dead after layer-4 gather)
  float*  sc51   = (float*) (ws + 7790592);         // 32,768
  float*  bi51   = (float*) (ws + 7823360);         // 32,768
  u16* wc2 = wbf, *wc3 = wbf + 8192, *wc4 = wbf + 24576;
  u16* w51b = wbf + 90112, *w52b = wbf + 614400;
  float* outf = (float*)d_out;
  float* gsL1 = gsum;        float* gsL2 = gsum + 256;  float* gsL3 = gsum + 512;
  float* gsL4 = gsum + 768;  float* gs51 = gsum + 1280; float* gs52 = gsum + 1536;

  k_pack_coords<<<64, 256, 0, stream>>>(x, c4, gsum);
  k_pack_w<<<4448, 256, 0, stream>>>(w2a, w2b, w3a, w3b, w4a, w4b, w51, w52, wbf);
  k_knn<<<4096, 256, 0, stream>>>(c4, idxp);

  // layer 1: fused conv+stats -> fused gather+GN
  k_conv1<<<128, 256, 0, stream>>>(x, w1a, w1b, g1a, g1b, convAB, gsL1);
  k_gather<<<512, 256, 0, stream>>>(convAB, 128, 64, 3, 16, gsL1,
                                    g1a, b1a, g1b, b1b, idxp, 20, xcat, 0, 3);

  // layer 2
  k_gemm<0,1,0><<<dim3(256,1), 256, 0, stream>>>(xcat + 0, 512, wc2, 64, convAB, 128,
                                                 3, 16, gsL2, g2a, g2b, 64, nullptr, nullptr);
  k_gather<<<512, 256, 0, stream>>>(convAB, 128, 64, 3, 16, gsL2,
                                    g2a, b2a, g2b, b2b, idxp, 40, xcat, 64, 3);

  // layer 3
  k_gemm<0,1,0><<<dim3(256,2), 256, 0, stream>>>(xcat + 64, 512, wc3, 64, convAB, 256,
                                                 4, 16, gsL3, g3a, g3b, 128, nullptr, nullptr);
  k_gather<<<1024, 256, 0, stream>>>(convAB, 256, 128, 4, 16, gsL3,
                                     g3a, b3a, g3b, b3b, idxp, 60, xcat, 128, 4);

  // layer 4
  k_gemm<0,1,0><<<dim3(256,4), 256, 0, stream>>>(xcat + 128, 512, wc4, 128, convAB, 512,
                                                 4, 32, gsL4, g4a, g4b, 256, nullptr, nullptr);
  k_gather<<<2048, 256, 0, stream>>>(convAB, 512, 256, 4, 32, gsL4,
                                     g4a, b4a, g4b, b4b, idxp, 80, xcat, 256, 5);

  // layer 5_1 (512->1024): GEMM(raw out)+stats; GN folded into scale/bias tables
  k_gemm<0,0,0><<<dim3(256,8), 256, 0, stream>>>(xcat, 512, w51b, 512, h1, 1024,
                                                 6, 16, gs51, g51, g51, 1024, nullptr, nullptr);
  k_sb51<<<32, 256, 0, stream>>>(gs51, g51, b51, sc51, bi51);

  // layer 5_2 (1024->512): GEMM(f32 out)+stats with fused A-transform (GN+LReLU of 5_1)
  k_gemm<1,0,1><<<dim3(256,4), 256, 0, stream>>>(h1, 1024, w52b, 1024, (void*)outf, 512,
                                                 5, 16, gs52, g52, g52, 512, sc51, bi51);
  k_apply52<<<8192, 256, 0, stream>>>(outf, gs52, g52, b52);
}

// Round 15
// 250.081 us; speedup vs baseline: 1.0977x; 1.0977x over previous
//
#include <hip/hip_runtime.h>
#include <stdint.h>

typedef unsigned short u16;
typedef unsigned int u32;
typedef unsigned long long u64;
typedef __attribute__((ext_vector_type(8))) __bf16 bf16x8;
typedef __attribute__((ext_vector_type(8))) u16 u16x8;
typedef __attribute__((ext_vector_type(4))) float f32x4;

#define DEVI __device__ __forceinline__

DEVI u16 f2bf(float f) {                    // fp32 -> bf16 RNE
  u32 u = __float_as_uint(f);
  u += 0x7FFFu + ((u >> 16) & 1u);
  return (u16)(u >> 16);
}
DEVI float bf2f(u16 h) { return __uint_as_float(((u32)h) << 16); }
DEVI u16 mono(u16 b) {                      // order-isomorphic bf16 -> u16
  return (b & 0x8000u) ? (u16)~b : (u16)(b | 0x8000u);
}
DEVI u16 unmono(u16 t) {
  return (t & 0x8000u) ? (u16)(t ^ 0x8000u) : (u16)(~t);
}

DEVI void glds16(const void* g, void* l) {  // 16B-per-lane global->LDS DMA
  __builtin_amdgcn_global_load_lds((const __attribute__((address_space(1))) void*)g,
                                   (__attribute__((address_space(3))) void*)l, 16, 0, 0);
}

// ---------------- prep: weights->bf16, coords pack, gsum zero (merged) ----------------
__global__ void k_pack_all(const float* __restrict__ x, float4* __restrict__ c4,
                           float* __restrict__ gsum,
                           const float* __restrict__ w2a, const float* __restrict__ w2b,
                           const float* __restrict__ w3a, const float* __restrict__ w3b,
                           const float* __restrict__ w4a, const float* __restrict__ w4b,
                           const float* __restrict__ w51, const float* __restrict__ w52,
                           u16* __restrict__ wbf) {
  int g = blockIdx.x * 256 + threadIdx.x;          // grid 4448*256 = 1,138,688 exact
  if (g < 1792) gsum[g] = 0.f;
  if (g < 16384) {
    float x0 = x[g*3], x1 = x[g*3+1], x2 = x[g*3+2];
    float n = __fadd_rn(__fadd_rn(__fmul_rn(x0,x0), __fmul_rn(x1,x1)), __fmul_rn(x2,x2));
    c4[g] = make_float4(x0, x1, x2, n);
  }
  const float* s; int off;
  if      (g <    4096) { s = w2a; off = g; }
  else if (g <    8192) { s = w2b; off = g - 4096; }
  else if (g <   16384) { s = w3a; off = g - 8192; }
  else if (g <   24576) { s = w3b; off = g - 16384; }
  else if (g <   57344) { s = w4a; off = g - 24576; }
  else if (g <   90112) { s = w4b; off = g - 57344; }
  else if (g <  614400) { s = w51; off = g - 90112; }
  else                  { s = w52; off = g - 614400; }
  wbf[g] = f2bf(s[off]);
}

// ---------------- knn: per-row top-80 (R5 structure; 64-VGPR tier forced) ----------------
__global__ __launch_bounds__(256, 8) void k_knn(const float4* __restrict__ c4, int* __restrict__ idxp) {
  __shared__ u64 cand[4][128];
  const int wid = threadIdx.x >> 6;
  const int lane = threadIdx.x & 63;
  const int batch = blockIdx.x & 7;
  const int qib = (blockIdx.x >> 3) * 4 + wid;      // query within batch
  const int blk = (batch << 11) + qib;
  const float4* cb = c4 + (batch << 11);
  const float4 q = cb[qib];

  u32 key[32];
  #pragma unroll
  for (int s = 0; s < 32; ++s) {
    float4 c = cb[s*64 + lane];
    float inner = __fadd_rn(__fadd_rn(__fmul_rn(q.x,c.x), __fmul_rn(q.y,c.y)), __fmul_rn(q.z,c.z));
    float pd = __fsub_rn(__fsub_rn(__fmul_rn(2.0f, inner), q.w), c.w);
    u32 bits = __float_as_uint(pd);
    key[s] = (bits & 0x80000000u) ? ~bits : (bits | 0x80000000u);
  }

  u32 T = 0;
  for (int bit = 30; bit >= 0; --bit) {
    u32 Tc = T | (1u << bit);
    int c = 0;
    #pragma unroll
    for (int s = 0; s < 32; ++s)
      c += __popcll(__ballot(key[s] >= Tc));
    if (c >= 80) { T = Tc; if (c <= 128) break; }
  }

  cand[wid][lane] = 0ull;
  cand[wid][lane + 64] = 0ull;
  asm volatile("s_waitcnt lgkmcnt(0)" ::: "memory");

  const u64 below = (lane == 0) ? 0ull : (~0ull >> (64 - lane));
  int base = 0;
  #pragma unroll
  for (int s = 0; s < 32; ++s) {
    u64 msk = __ballot(key[s] >= T);
    if (key[s] >= T) {
      int pos = base + (int)__popcll(msk & below);
      if (pos < 128)
        cand[wid][pos] = (((u64)key[s]) << 32) | (u32)(2047 - (s*64 + lane));
    }
    base += (int)__popcll(msk);
  }
  asm volatile("s_waitcnt lgkmcnt(0)" ::: "memory");

  u64 v0 = cand[wid][lane];
  u64 v1 = cand[wid][lane + 64];
  #pragma unroll
  for (int k2 = 2; k2 <= 128; k2 <<= 1) {
    #pragma unroll
    for (int j = k2 >> 1; j > 0; j >>= 1) {
      if (j == 64) {                                // cross-slot, in-lane
        u64 mx = v0 > v1 ? v0 : v1;
        u64 mn = v0 > v1 ? v1 : v0;
        v0 = mx; v1 = mn;
      } else {
        u64 p0 = __shfl_xor(v0, j, 64);
        u64 p1 = __shfl_xor(v1, j, 64);
        bool lowlane = ((lane & j) == 0);
        bool d0 = ((lane & k2) == 0);
        bool d1 = (((lane + 64) & k2) == 0);
        bool wm0 = (d0 == lowlane);
        bool wm1 = (d1 == lowlane);
        u64 mx0 = v0 > p0 ? v0 : p0, mn0 = v0 > p0 ? p0 : v0;
        u64 mx1 = v1 > p1 ? v1 : p1, mn1 = v1 > p1 ? p1 : v1;
        v0 = wm0 ? mx0 : mn0;
        v1 = wm1 ? mx1 : mn1;
      }
    }
  }

  idxp[(size_t)blk*80 + lane] = 2047 - (int)(u32)v0;
  if (lane < 16) idxp[(size_t)blk*80 + 64 + lane] = 2047 - (int)(u32)v1;
}

// ---------------- layer 1 conv (K=3, fp32) + fused stats, store mono' ----------------
__global__ __launch_bounds__(256) void k_conv1(const float* __restrict__ x,
    const float* __restrict__ w1a, const float* __restrict__ w1b,
    const float* __restrict__ g1a, const float* __restrict__ g1b,
    u16* __restrict__ out, float* __restrict__ gsum) {
  __shared__ float xs[384];
  __shared__ float colsum[128], colss[128];
  const int tid = threadIdx.x;
  const int P0 = blockIdx.x * 128;
  for (int i = tid; i < 384; i += 256) xs[i] = x[P0*3 + i];
  if (tid < 128) { colsum[tid] = 0.f; colss[tid] = 0.f; }
  __syncthreads();

  const int c = tid & 127;
  const int half = tid >> 7;
  const float* w = (c < 64) ? (w1a + 3*c) : (w1b + 3*(c-64));
  float wx = w[0], wy = w[1], wz = w[2];
  float gam = (c < 64) ? g1a[c] : g1b[c-64];
  u16 flip = (gam < 0.f) ? (u16)0xFFFF : (u16)0;

  float s = 0.f, ss = 0.f;
  #pragma unroll 4
  for (int p_ = 0; p_ < 64; ++p_) {
    int p = (half << 6) + p_;
    float h = wx*xs[p*3] + wy*xs[p*3+1] + wz*xs[p*3+2];
    s += h; ss += h*h;
    out[(size_t)(P0 + p)*128 + c] = (u16)(mono(f2bf(h)) ^ flip);
  }
  atomicAdd(&colsum[c], s);
  atomicAdd(&colss[c], ss);
  __syncthreads();
  if (tid < 16) {
    float gs = 0.f, gss = 0.f;
    #pragma unroll
    for (int q = 0; q < 8; ++q) { gs += colsum[tid*8+q]; gss += colss[tid*8+q]; }
    int b = blockIdx.x >> 4;
    atomicAdd(&gsum[(b*16 + tid)*2],   gs);
    atomicAdd(&gsum[(b*16 + tid)*2+1], gss);
  }
}

// ---------------- fused gather-max + GroupNorm + LeakyReLU + add-fb ----------------
__global__ __launch_bounds__(256) void k_gather(const u16* __restrict__ conv, int Ctot, int Ca,
    int CgShift, int NG, const float* __restrict__ gsum,
    const float* __restrict__ ga, const float* __restrict__ ba,
    const float* __restrict__ gb, const float* __restrict__ bb,
    const int* __restrict__ idxp, int k,
    u16* __restrict__ xcat, int outOff, int lppShift) {
  const int batch = blockIdx.x & 7;
  const int blkin = blockIdx.x >> 3;
  const int lgid = blkin * 256 + threadIdx.x;
  const int p_in = lgid >> lppShift;
  const int c8 = (lgid & ((1 << lppShift) - 1)) * 8;
  const int p = (batch << 11) + p_in;
  const int* irow = idxp + (size_t)p * 80;
  const u16* cb = conv + ((size_t)(batch << 11)) * Ctot + c8;

  const int gia = c8 >> CgShift;
  const int gib = (Ca + c8) >> CgShift;
  const float cnt = (float)(2048 << CgShift);
  float2 sa = *(const float2*)(gsum + (size_t)(batch*NG + gia)*2);
  float2 sb = *(const float2*)(gsum + (size_t)(batch*NG + gib)*2);
  float meanA = sa.x / cnt, rstdA = rsqrtf(sa.y / cnt - meanA*meanA + 1e-5f);
  float meanB = sb.x / cnt, rstdB = rsqrtf(sb.y / cnt - meanB*meanB + 1e-5f);

  float gav[8], bav[8], gbv[8], bbv[8];
  *(float4*)&gav[0] = *(const float4*)(ga + c8); *(float4*)&gav[4] = *(const float4*)(ga + c8 + 4);
  *(float4*)&bav[0] = *(const float4*)(ba + c8); *(float4*)&bav[4] = *(const float4*)(ba + c8 + 4);
  *(float4*)&gbv[0] = *(const float4*)(gb + c8); *(float4*)&gbv[4] = *(const float4*)(gb + c8 + 4);
  *(float4*)&bbv[0] = *(const float4*)(bb + c8); *(float4*)&bbv[4] = *(const float4*)(bb + c8 + 4);

  u16x8 fbv = *(const u16x8*)(conv + (size_t)p * Ctot + Ca + c8);

  u16x8 m8 = (u16x8)(u16)0;
  for (int j0 = 0; j0 < k; j0 += 4) {
    int4 mi4 = *(const int4*)(irow + j0);
    int mis[4] = {mi4.x, mi4.y, mi4.z, mi4.w};
    u16x8 rows[4];
    #pragma unroll
    for (int u = 0; u < 4; ++u)
      rows[u] = *(const u16x8*)(cb + (size_t)mis[u] * Ctot);
    #pragma unroll
    for (int u = 0; u < 4; ++u)
      m8 = __builtin_elementwise_max(m8, rows[u]);   // v_pk_max_u16
  }

  u16 ov[8];
  #pragma unroll
  for (int q = 0; q < 8; ++q) {
    u16 fA = (gav[q] < 0.f) ? (u16)0xFFFF : (u16)0;
    u16 fB = (gbv[q] < 0.f) ? (u16)0xFFFF : (u16)0;
    float xa = bf2f(unmono((u16)((u16)m8[q] ^ fA)));
    float ha = (xa - meanA) * rstdA * gav[q] + bav[q];
    ha = ha > 0.f ? ha : 0.2f * ha;
    float xb = bf2f(unmono((u16)((u16)fbv[q] ^ fB)));
    float hb = (xb - meanB) * rstdB * gbv[q] + bbv[q];
    hb = hb > 0.f ? hb : 0.2f * hb;
    ov[q] = f2bf(ha + hb);
  }
  *(u16x8*)(xcat + (size_t)p * 512 + outOff + c8) = *(u16x8*)ov;
}

// ---------------- scale/bias tables for layer 5_1 GN (replaces apply51 pass) ----------------
__global__ void k_sb51(const float* __restrict__ gsum, const float* __restrict__ g,
                       const float* __restrict__ b, float* __restrict__ sc,
                       float* __restrict__ bi) {
  int i = blockIdx.x * 256 + threadIdx.x;            // < 8192 (8 batches x 1024 ch)
  int bb = i >> 10, c = i & 1023;
  int grp = c >> 6;
  float2 s = *(const float2*)(gsum + (size_t)(bb*16 + grp)*2);
  float mean = s.x / 131072.f;
  float rstd = rsqrtf(s.y / 131072.f - mean*mean + 1e-5f);
  float A = rstd * g[c];
  sc[i] = A;
  bi[i] = b[c] - mean * A;
}

// ---------------- GN apply + LeakyReLU (layer 5_2): bf16 in, f32 out ----------------
__global__ __launch_bounds__(256) void k_apply52(const u16* __restrict__ h2,
    float* __restrict__ outp, const float* __restrict__ gsum,
    const float* __restrict__ g, const float* __restrict__ b) {
  int gid = blockIdx.x * 256 + threadIdx.x;          // grid 4096 -> 8 elems/thread
  size_t e = (size_t)gid * 8;
  int row = (int)(e >> 9);                           // Ctot = 512
  int c = (int)e & 511;
  int grp = c >> 5;
  float2 s = *(const float2*)(gsum + (size_t)((row >> 11)*16 + grp)*2);
  const float cnt = 65536.f;
  float mean = s.x / cnt, rstd = rsqrtf(s.y / cnt - mean*mean + 1e-5f);
  u16x8 v = *(const u16x8*)(h2 + e);
  float gv[8], bv[8];
  *(float4*)&gv[0] = *(const float4*)(g + c); *(float4*)&gv[4] = *(const float4*)(g + c + 4);
  *(float4*)&bv[0] = *(const float4*)(b + c); *(float4*)&bv[4] = *(const float4*)(b + c + 4);
  float h[8];
  #pragma unroll
  for (int q = 0; q < 8; ++q) {
    float xv = bf2f((u16)v[q]);
    float o = (xv - mean) * rstd * gv[q] + bv[q];
    h[q] = o > 0.f ? o : 0.2f * o;
  }
  *(float4*)(outp + e)     = make_float4(h[0], h[1], h[2], h[3]);
  *(float4*)(outp + e + 4) = make_float4(h[4], h[5], h[6], h[7]);
}

// ---------------- bf16 MFMA GEMM + fused GN stats (+ mono' store / A-transform) ----------------
// R9 structure (best measured): single-buffer 2-barrier, glds16 staging, scalar C stores.
template<int OUTF32, int MONO, int TRANSA>
__global__ __launch_bounds__(256) void k_gemm(const u16* __restrict__ A, int lda,
    const u16* __restrict__ Bw, int K, void* __restrict__ outp, int ldc,
    int CgShift, int NG, float* __restrict__ gsum,
    const float* __restrict__ ga, const float* __restrict__ gb, int Ca,
    const float* __restrict__ scA, const float* __restrict__ biA) {
  constexpr int BK = 64;
  __shared__ __align__(16) u16 As[128 * BK];
  __shared__ __align__(16) u16 Bs[128 * BK];
  __shared__ float colsum[128], colss[128];
  const int tid = threadIdx.x;
  const int wid = tid >> 6, lane = tid & 63;
  const int tileM = blockIdx.x * 128, tileN = blockIdx.y * 128;
  const int wm = wid >> 1, wn = wid & 1;
  const int lr = lane & 15, lk = (lane >> 4) * 8;
  const float* scb = TRANSA ? (scA + (size_t)(tileM >> 11) * 1024) : nullptr;
  const float* bib = TRANSA ? (biA + (size_t)(tileM >> 11) * 1024) : nullptr;
  f32x4 acc[4][4] = {};
  for (int k0 = 0; k0 < K; k0 += BK) {
    __syncthreads();
    #pragma unroll
    for (int i = 0; i < 4; ++i) {
      int flat = i * 256 + tid;
      int row = flat >> 3, ck = flat & 7;
      if (TRANSA) {
        int cbase = k0 + ck * 8;
        uint4 v = *(const uint4*)(A + (size_t)(tileM + row) * lda + cbase);
        float4 s0 = *(const float4*)(scb + cbase);
        float4 s1 = *(const float4*)(scb + cbase + 4);
        float4 b0 = *(const float4*)(bib + cbase);
        float4 b1 = *(const float4*)(bib + cbase + 4);
        float sc8[8] = {s0.x,s0.y,s0.z,s0.w,s1.x,s1.y,s1.z,s1.w};
        float bi8[8] = {b0.x,b0.y,b0.z,b0.w,b1.x,b1.y,b1.z,b1.w};
        u32 vv[4] = {v.x, v.y, v.z, v.w};
        u32 ov[4];
        #pragma unroll
        for (int q2 = 0; q2 < 4; ++q2) {
          float x0 = bf2f((u16)(vv[q2] & 0xFFFF));
          float x1 = bf2f((u16)(vv[q2] >> 16));
          float o0 = x0 * sc8[q2*2]   + bi8[q2*2];
          float o1 = x1 * sc8[q2*2+1] + bi8[q2*2+1];
          o0 = o0 > 0.f ? o0 : 0.2f * o0;
          o1 = o1 > 0.f ? o1 : 0.2f * o1;
          ov[q2] = (u32)f2bf(o0) | (((u32)f2bf(o1)) << 16);
        }
        *(uint4*)((char*)As + flat * 16) = make_uint4(ov[0], ov[1], ov[2], ov[3]);
      } else {
        glds16(A + (size_t)(tileM + row) * lda + (k0 + ck * 8), (char*)As + flat * 16);
      }
    }
    #pragma unroll
    for (int i = 0; i < 4; ++i) {
      int flat = i * 256 + tid;
      int row = flat >> 3, ck = flat & 7;
      glds16(Bw + (size_t)(tileN + row) * K + (k0 + ck * 8), (char*)Bs + flat * 16);
    }
    __syncthreads();
    #pragma unroll
    for (int ks = 0; ks < 2; ++ks) {
      bf16x8 af[4], bfr[4];
      #pragma unroll
      for (int i = 0; i < 4; ++i)
        af[i] = *(const bf16x8*)&As[(wm*64 + i*16 + lr) * BK + ks*32 + lk];
      #pragma unroll
      for (int j = 0; j < 4; ++j)
        bfr[j] = *(const bf16x8*)&Bs[(wn*64 + j*16 + lr) * BK + ks*32 + lk];
      #pragma unroll
      for (int i = 0; i < 4; ++i)
        #pragma unroll
        for (int j = 0; j < 4; ++j)
          acc[i][j] = __builtin_amdgcn_mfma_f32_16x16x32_bf16(af[i], bfr[j], acc[i][j], 0, 0, 0);
    }
  }
  const int orow0 = tileM + wm*64 + ((lane >> 4) * 4);
  const int ocol0 = tileN + wn*64 + lr;

  u16 flip[4] = {0,0,0,0};
  if (MONO) {
    #pragma unroll
    for (int j = 0; j < 4; ++j) {
      int colg = ocol0 + j*16;
      float gm = (colg < Ca) ? ga[colg] : gb[colg - Ca];
      flip[j] = (gm < 0.f) ? (u16)0xFFFF : (u16)0;
    }
  }

  float csum[4] = {0.f,0.f,0.f,0.f}, css[4] = {0.f,0.f,0.f,0.f};
  #pragma unroll
  for (int i = 0; i < 4; ++i)
    #pragma unroll
    for (int j = 0; j < 4; ++j)
      #pragma unroll
      for (int r = 0; r < 4; ++r) {
        int row = orow0 + i*16 + r;
        int col = ocol0 + j*16;
        float v = acc[i][j][r];
        csum[j] += v; css[j] += v*v;
        if (OUTF32) ((float*)outp)[(size_t)row * ldc + col] = v;
        else {
          u16 st = f2bf(v);
          if (MONO) st = (u16)(mono(st) ^ flip[j]);
          ((u16*)outp)[(size_t)row * ldc + col] = st;
        }
      }

  #pragma unroll
  for (int mask = 16; mask <= 32; mask <<= 1)
    #pragma unroll
    for (int j = 0; j < 4; ++j) {
      csum[j] += __shfl_xor(csum[j], mask, 64);
      css[j]  += __shfl_xor(css[j],  mask, 64);
    }
  if (tid < 128) { colsum[tid] = 0.f; colss[tid] = 0.f; }
  __syncthreads();
  if ((lane >> 4) == 0) {
    #pragma unroll
    for (int j = 0; j < 4; ++j) {
      int col = wn*64 + j*16 + lr;
      atomicAdd(&colsum[col], csum[j]);
      atomicAdd(&colss[col],  css[j]);
    }
  }
  __syncthreads();
  const int NGtile = 128 >> CgShift;
  if (tid < NGtile) {
    float s = 0.f, ss = 0.f;
    const int Cg = 1 << CgShift;
    for (int c0 = tid << CgShift; c0 < (tid << CgShift) + Cg; ++c0) { s += colsum[c0]; ss += colss[c0]; }
    int b = tileM >> 11;
    int gidx = (tileN >> CgShift) + tid;
    atomicAdd(&gsum[(size_t)(b*NG + gidx)*2],   s);
    atomicAdd(&gsum[(size_t)(b*NG + gidx)*2+1], ss);
  }
}

// ---------------- launch ----------------
extern "C" void kernel_launch(void* const* d_in, const int* in_sizes, int n_in,
                              void* d_out, int out_size, void* d_ws, size_t ws_size,
                              hipStream_t stream) {
  const float* x   = (const float*)d_in[0];
  const float* w1a = (const float*)d_in[1];
  const float* g1a = (const float*)d_in[2];
  const float* b1a = (const float*)d_in[3];
  const float* w1b = (const float*)d_in[4];
  const float* g1b = (const float*)d_in[5];
  const float* b1b = (const float*)d_in[6];
  const float* w2a = (const float*)d_in[7];
  const float* g2a = (const float*)d_in[8];
  const float* b2a = (const float*)d_in[9];
  const float* w2b = (const float*)d_in[10];
  const float* g2b = (const float*)d_in[11];
  const float* b2b = (const float*)d_in[12];
  const float* w3a = (const float*)d_in[13];
  const float* g3a = (const float*)d_in[14];
  const float* b3a = (const float*)d_in[15];
  const float* w3b = (const float*)d_in[16];
  const float* g3b = (const float*)d_in[17];
  const float* b3b = (const float*)d_in[18];
  const float* w4a = (const float*)d_in[19];
  const float* g4a = (const float*)d_in[20];
  const float* b4a = (const float*)d_in[21];
  const float* w4b = (const float*)d_in[22];
  const float* g4b = (const float*)d_in[23];
  const float* b4b = (const float*)d_in[24];
  const float* w51 = (const float*)d_in[25];
  const float* g51 = (const float*)d_in[26];
  const float* b51 = (const float*)d_in[27];
  const float* w52 = (const float*)d_in[28];
  const float* g52 = (const float*)d_in[29];
  const float* b52 = (const float*)d_in[30];

  char* ws = (char*)d_ws;
  int*    idxp   = (int*)   (ws + 0);               // 5,242,880 (dead after L4 gather)
  float4* c4     = (float4*)(ws + 5242880);         // 262,144
  u16*    wbf    = (u16*)   (ws + 5505024);         // 2,277,376
  float*  gsum   = (float*) (ws + 7782400);         // 8,192
  u16*    convAB = (u16*)   (ws + 7790592);         // 16,777,216 (dead after L4 gather)
  u16*    h1     = (u16*)   (ws + 24567808);        // 33,554,432
  u16*    xcat   = (u16*)   (ws + 58122240);        // 16,777,216
  // after L4 gather: sc51/bi51 live in idxp region; h2 (bf16 5_2 out) in convAB region
  float*  sc51   = (float*) (ws + 0);               // 32,768
  float*  bi51   = (float*) (ws + 32768);           // 32,768
  u16*    h2     = (u16*)   (ws + 7790592);         // 16,777,216 (16384*512*2)
  u16* wc2 = wbf, *wc3 = wbf + 8192, *wc4 = wbf + 24576;
  u16* w51b = wbf + 90112, *w52b = wbf + 614400;
  float* outf = (float*)d_out;
  float* gsL1 = gsum;        float* gsL2 = gsum + 256;  float* gsL3 = gsum + 512;
  float* gsL4 = gsum + 768;  float* gs51 = gsum + 1280; float* gs52 = gsum + 1536;

  k_pack_all<<<4448, 256, 0, stream>>>(x, c4, gsum, w2a, w2b, w3a, w3b, w4a, w4b,
                                       w51, w52, wbf);
  k_knn<<<4096, 256, 0, stream>>>(c4, idxp);

  // layer 1: fused conv+stats -> fused gather+GN
  k_conv1<<<128, 256, 0, stream>>>(x, w1a, w1b, g1a, g1b, convAB, gsL1);
  k_gather<<<512, 256, 0, stream>>>(convAB, 128, 64, 3, 16, gsL1,
                                    g1a, b1a, g1b, b1b, idxp, 20, xcat, 0, 3);

  // layer 2
  k_gemm<0,1,0><<<dim3(128,1), 256, 0, stream>>>(xcat + 0, 512, wc2, 64, convAB, 128,
                                                 3, 16, gsL2, g2a, g2b, 64, nullptr, nullptr);
  k_gather<<<512, 256, 0, stream>>>(convAB, 128, 64, 3, 16, gsL2,
                                    g2a, b2a, g2b, b2b, idxp, 40, xcat, 64, 3);

  // layer 3
  k_gemm<0,1,0><<<dim3(128,2), 256, 0, stream>>>(xcat + 64, 512, wc3, 64, convAB, 256,
                                                 4, 16, gsL3, g3a, g3b, 128, nullptr, nullptr);
  k_gather<<<1024, 256, 0, stream>>>(convAB, 256, 128, 4, 16, gsL3,
                                     g3a, b3a, g3b, b3b, idxp, 60, xcat, 128, 4);

  // layer 4
  k_gemm<0,1,0><<<dim3(128,4), 256, 0, stream>>>(xcat + 128, 512, wc4, 128, convAB, 512,
                                                 4, 32, gsL4, g4a, g4b, 256, nullptr, nullptr);
  k_gather<<<2048, 256, 0, stream>>>(convAB, 512, 256, 4, 32, gsL4,
                                     g4a, b4a, g4b, b4b, idxp, 80, xcat, 256, 5);

  // layer 5_1 (512->1024): GEMM(raw out)+stats; GN folded into scale/bias tables
  k_gemm<0,0,0><<<dim3(128,8), 256, 0, stream>>>(xcat, 512, w51b, 512, h1, 1024,
                                                 6, 16, gs51, g51, g51, 1024, nullptr, nullptr);
  k_sb51<<<32, 256, 0, stream>>>(gs51, g51, b51, sc51, bi51);

  // layer 5_2 (1024->512): GEMM(bf16 out -> h2)+stats, fused A-transform (GN+LReLU of 5_1)
  k_gemm<0,0,1><<<dim3(128,4), 256, 0, stream>>>(h1, 1024, w52b, 1024, h2, 512,
                                                 5, 16, gs52, g52, g52, 512, sc51, bi51);
  // final GN apply: bf16 h2 -> f32 d_out (halves the apply pass's read traffic)
  k_apply52<<<4096, 256, 0, stream>>>(h2, outf, gs52, g52, b52);
}

// Round 17
// 244.548 us; speedup vs baseline: 1.1226x; 1.0226x over previous
//
#include <hip/hip_runtime.h>
#include <stdint.h>

typedef unsigned short u16;
typedef unsigned int u32;
typedef unsigned long long u64;
typedef __attribute__((ext_vector_type(8))) __bf16 bf16x8;
typedef __attribute__((ext_vector_type(8))) u16 u16x8;
typedef __attribute__((ext_vector_type(4))) float f32x4;

#define DEVI __device__ __forceinline__

DEVI u16 f2bf(float f) {                    // fp32 -> bf16 RNE
  u32 u = __float_as_uint(f);
  u += 0x7FFFu + ((u >> 16) & 1u);
  return (u16)(u >> 16);
}
DEVI float bf2f(u16 h) { return __uint_as_float(((u32)h) << 16); }
DEVI u16 mono(u16 b) {                      // order-isomorphic bf16 -> u16
  return (b & 0x8000u) ? (u16)~b : (u16)(b | 0x8000u);
}
DEVI u16 unmono(u16 t) {
  return (t & 0x8000u) ? (u16)(t ^ 0x8000u) : (u16)(~t);
}

DEVI void glds16(const void* g, void* l) {  // 16B-per-lane global->LDS DMA
  __builtin_amdgcn_global_load_lds((const __attribute__((address_space(1))) void*)g,
                                   (__attribute__((address_space(3))) void*)l, 16, 0, 0);
}

// ---------------- prep: weights->bf16, coords pack, gsum zero (merged) ----------------
__global__ void k_pack_all(const float* __restrict__ x, float4* __restrict__ c4,
                           float* __restrict__ gsum,
                           const float* __restrict__ w2a, const float* __restrict__ w2b,
                           const float* __restrict__ w3a, const float* __restrict__ w3b,
                           const float* __restrict__ w4a, const float* __restrict__ w4b,
                           const float* __restrict__ w51, const float* __restrict__ w52,
                           u16* __restrict__ wbf) {
  int g = blockIdx.x * 256 + threadIdx.x;          // grid 4448*256 = 1,138,688 exact
  if (g < 1792) gsum[g] = 0.f;
  if (g < 16384) {
    float x0 = x[g*3], x1 = x[g*3+1], x2 = x[g*3+2];
    float n = __fadd_rn(__fadd_rn(__fmul_rn(x0,x0), __fmul_rn(x1,x1)), __fmul_rn(x2,x2));
    c4[g] = make_float4(x0, x1, x2, n);
  }
  const float* s; int off;
  if      (g <    4096) { s = w2a; off = g; }
  else if (g <    8192) { s = w2b; off = g - 4096; }
  else if (g <   16384) { s = w3a; off = g - 8192; }
  else if (g <   24576) { s = w3b; off = g - 16384; }
  else if (g <   57344) { s = w4a; off = g - 24576; }
  else if (g <   90112) { s = w4b; off = g - 57344; }
  else if (g <  614400) { s = w51; off = g - 90112; }
  else                  { s = w52; off = g - 614400; }
  wbf[g] = f2bf(s[off]);
}

// ---------------- knn (blocks 0..4095) + layer-1 conv (blocks 4096..4223), fused ----------------
// knn: R5 structure + M-prefix bisect skip. FIX vs R16: the skip's prefix invariant
// requires T to match Mh on bit 31 too; pd can round slightly POSITIVE (key > 0x80000000),
// making Mh's bit31 = 1 while T's is always 0. Such rows must disable the skip:
// onpfx starts as !(Mh & 0x80000000). All-negative-pd rows (the vast majority) keep skips.
__global__ __launch_bounds__(256, 8) void k_knn_conv1(
    const float4* __restrict__ c4, int* __restrict__ idxp,
    const float* __restrict__ x,
    const float* __restrict__ w1a, const float* __restrict__ w1b,
    const float* __restrict__ g1a, const float* __restrict__ g1b,
    u16* __restrict__ convout, float* __restrict__ gsum) {
  __shared__ u64 cand[4][128];
  __shared__ float xs[384];
  __shared__ float colsum[128], colss[128];
  const int tid = threadIdx.x;

  if (blockIdx.x >= 4096) {
    // ---------- conv1 path ----------
    const int P0 = (blockIdx.x - 4096) * 128;
    for (int i = tid; i < 384; i += 256) xs[i] = x[P0*3 + i];
    if (tid < 128) { colsum[tid] = 0.f; colss[tid] = 0.f; }
    __syncthreads();

    const int c = tid & 127;
    const int half = tid >> 7;
    const float* w = (c < 64) ? (w1a + 3*c) : (w1b + 3*(c-64));
    float wx = w[0], wy = w[1], wz = w[2];
    float gam = (c < 64) ? g1a[c] : g1b[c-64];
    u16 flip = (gam < 0.f) ? (u16)0xFFFF : (u16)0;

    float s = 0.f, ss = 0.f;
    #pragma unroll 4
    for (int p_ = 0; p_ < 64; ++p_) {
      int p = (half << 6) + p_;
      float h = wx*xs[p*3] + wy*xs[p*3+1] + wz*xs[p*3+2];
      s += h; ss += h*h;
      convout[(size_t)(P0 + p)*128 + c] = (u16)(mono(f2bf(h)) ^ flip);
    }
    atomicAdd(&colsum[c], s);
    atomicAdd(&colss[c], ss);
    __syncthreads();
    if (tid < 16) {
      float gs = 0.f, gss = 0.f;
      #pragma unroll
      for (int q = 0; q < 8; ++q) { gs += colsum[tid*8+q]; gss += colss[tid*8+q]; }
      int b = P0 >> 11;
      atomicAdd(&gsum[(b*16 + tid)*2],   gs);
      atomicAdd(&gsum[(b*16 + tid)*2+1], gss);
    }
    return;
  }

  // ---------- knn path ----------
  const int wid = tid >> 6;
  const int lane = tid & 63;
  const int batch = blockIdx.x & 7;
  const int qib = (blockIdx.x >> 3) * 4 + wid;      // query within batch
  const int blk = (batch << 11) + qib;
  const float4* cb = c4 + (batch << 11);
  const float4 q = cb[qib];

  u32 key[32];
  #pragma unroll
  for (int s = 0; s < 32; ++s) {
    float4 c = cb[s*64 + lane];
    float inner = __fadd_rn(__fadd_rn(__fmul_rn(q.x,c.x), __fmul_rn(q.y,c.y)), __fmul_rn(q.z,c.z));
    float pd = __fsub_rn(__fsub_rn(__fmul_rn(2.0f, inner), q.w), c.w);
    u32 bits = __float_as_uint(pd);
    key[s] = (bits & 0x80000000u) ? ~bits : (bits | 0x80000000u);
  }

  // wave-max of non-self keys (self key is exactly 0x80000000; excluded by value)
  u32 Mh = 0;
  #pragma unroll
  for (int s = 0; s < 32; ++s) {
    u32 kk = key[s];
    if (kk != 0x80000000u && kk > Mh) Mh = kk;
  }
  #pragma unroll
  for (int m = 32; m; m >>= 1) {
    u32 o = __shfl_xor(Mh, m, 64);
    if (o > Mh) Mh = o;
  }

  // radix bisect with prefix skip. Invariant: while onpfx, T == Mh on ALL bits above
  // `bit` (incl. bit 31, where T=0) -> Tc > Mh when Mh's bit is 0 -> count = #self < 80.
  // If Mh has bit31 set (a pd rounded positive), the invariant can't hold: no skips.
  u32 T = 0;
  bool onpfx = ((Mh & 0x80000000u) == 0u);
  for (int bit = 30; bit >= 0; --bit) {
    if (onpfx && !((Mh >> bit) & 1u)) continue;
    u32 Tc = T | (1u << bit);
    int c = 0;
    #pragma unroll
    for (int s = 0; s < 32; ++s)
      c += __popcll(__ballot(key[s] >= Tc));
    if (c >= 80) { T = Tc; if (c <= 128) break; }
    else onpfx = false;
  }

  cand[wid][lane] = 0ull;
  cand[wid][lane + 64] = 0ull;
  asm volatile("s_waitcnt lgkmcnt(0)" ::: "memory");

  const u64 below = (lane == 0) ? 0ull : (~0ull >> (64 - lane));
  int base = 0;
  #pragma unroll
  for (int s = 0; s < 32; ++s) {
    u64 msk = __ballot(key[s] >= T);
    if (key[s] >= T) {
      int pos = base + (int)__popcll(msk & below);
      if (pos < 128)
        cand[wid][pos] = (((u64)key[s]) << 32) | (u32)(2047 - (s*64 + lane));
    }
    base += (int)__popcll(msk);
  }
  asm volatile("s_waitcnt lgkmcnt(0)" ::: "memory");

  u64 v0 = cand[wid][lane];
  u64 v1 = cand[wid][lane + 64];
  #pragma unroll
  for (int k2 = 2; k2 <= 128; k2 <<= 1) {
    #pragma unroll
    for (int j = k2 >> 1; j > 0; j >>= 1) {
      if (j == 64) {                                // cross-slot, in-lane
        u64 mx = v0 > v1 ? v0 : v1;
        u64 mn = v0 > v1 ? v1 : v0;
        v0 = mx; v1 = mn;
      } else {
        u64 p0 = __shfl_xor(v0, j, 64);
        u64 p1 = __shfl_xor(v1, j, 64);
        bool lowlane = ((lane & j) == 0);
        bool d0 = ((lane & k2) == 0);
        bool d1 = (((lane + 64) & k2) == 0);
        bool wm0 = (d0 == lowlane);
        bool wm1 = (d1 == lowlane);
        u64 mx0 = v0 > p0 ? v0 : p0, mn0 = v0 > p0 ? p0 : v0;
        u64 mx1 = v1 > p1 ? v1 : p1, mn1 = v1 > p1 ? p1 : v1;
        v0 = wm0 ? mx0 : mn0;
        v1 = wm1 ? mx1 : mn1;
      }
    }
  }

  idxp[(size_t)blk*80 + lane] = 2047 - (int)(u32)v0;
  if (lane < 16) idxp[(size_t)blk*80 + 64 + lane] = 2047 - (int)(u32)v1;
}

// ---------------- fused gather-max + GroupNorm + LeakyReLU + add-fb ----------------
__global__ __launch_bounds__(256) void k_gather(const u16* __restrict__ conv, int Ctot, int Ca,
    int CgShift, int NG, const float* __restrict__ gsum,
    const float* __restrict__ ga, const float* __restrict__ ba,
    const float* __restrict__ gb, const float* __restrict__ bb,
    const int* __restrict__ idxp, int k,
    u16* __restrict__ xcat, int outOff, int lppShift) {
  const int batch = blockIdx.x & 7;
  const int blkin = blockIdx.x >> 3;
  const int lgid = blkin * 256 + threadIdx.x;
  const int p_in = lgid >> lppShift;
  const int c8 = (lgid & ((1 << lppShift) - 1)) * 8;
  const int p = (batch << 11) + p_in;
  const int* irow = idxp + (size_t)p * 80;
  const u16* cb = conv + ((size_t)(batch << 11)) * Ctot + c8;

  const int gia = c8 >> CgShift;
  const int gib = (Ca + c8) >> CgShift;
  const float cnt = (float)(2048 << CgShift);
  float2 sa = *(const float2*)(gsum + (size_t)(batch*NG + gia)*2);
  float2 sb = *(const float2*)(gsum + (size_t)(batch*NG + gib)*2);
  float meanA = sa.x / cnt, rstdA = rsqrtf(sa.y / cnt - meanA*meanA + 1e-5f);
  float meanB = sb.x / cnt, rstdB = rsqrtf(sb.y / cnt - meanB*meanB + 1e-5f);

  float gav[8], bav[8], gbv[8], bbv[8];
  *(float4*)&gav[0] = *(const float4*)(ga + c8); *(float4*)&gav[4] = *(const float4*)(ga + c8 + 4);
  *(float4*)&bav[0] = *(const float4*)(ba + c8); *(float4*)&bav[4] = *(const float4*)(ba + c8 + 4);
  *(float4*)&gbv[0] = *(const float4*)(gb + c8); *(float4*)&gbv[4] = *(const float4*)(gb + c8 + 4);
  *(float4*)&bbv[0] = *(const float4*)(bb + c8); *(float4*)&bbv[4] = *(const float4*)(bb + c8 + 4);

  u16x8 fbv = *(const u16x8*)(conv + (size_t)p * Ctot + Ca + c8);

  u16x8 m8 = (u16x8)(u16)0;
  for (int j0 = 0; j0 < k; j0 += 4) {
    int4 mi4 = *(const int4*)(irow + j0);
    int mis[4] = {mi4.x, mi4.y, mi4.z, mi4.w};
    u16x8 rows[4];
    #pragma unroll
    for (int u = 0; u < 4; ++u)
      rows[u] = *(const u16x8*)(cb + (size_t)mis[u] * Ctot);
    #pragma unroll
    for (int u = 0; u < 4; ++u)
      m8 = __builtin_elementwise_max(m8, rows[u]);   // v_pk_max_u16
  }

  u16 ov[8];
  #pragma unroll
  for (int q = 0; q < 8; ++q) {
    u16 fA = (gav[q] < 0.f) ? (u16)0xFFFF : (u16)0;
    u16 fB = (gbv[q] < 0.f) ? (u16)0xFFFF : (u16)0;
    float xa = bf2f(unmono((u16)((u16)m8[q] ^ fA)));
    float ha = (xa - meanA) * rstdA * gav[q] + bav[q];
    ha = ha > 0.f ? ha : 0.2f * ha;
    float xb = bf2f(unmono((u16)((u16)fbv[q] ^ fB)));
    float hb = (xb - meanB) * rstdB * gbv[q] + bbv[q];
    hb = hb > 0.f ? hb : 0.2f * hb;
    ov[q] = f2bf(ha + hb);
  }
  *(u16x8*)(xcat + (size_t)p * 512 + outOff + c8) = *(u16x8*)ov;
}

// ---------------- scale/bias tables for layer 5_1 GN (replaces apply51 pass) ----------------
__global__ void k_sb51(const float* __restrict__ gsum, const float* __restrict__ g,
                       const float* __restrict__ b, float* __restrict__ sc,
                       float* __restrict__ bi) {
  int i = blockIdx.x * 256 + threadIdx.x;            // < 8192 (8 batches x 1024 ch)
  int bb = i >> 10, c = i & 1023;
  int grp = c >> 6;
  float2 s = *(const float2*)(gsum + (size_t)(bb*16 + grp)*2);
  float mean = s.x / 131072.f;
  float rstd = rsqrtf(s.y / 131072.f - mean*mean + 1e-5f);
  float A = rstd * g[c];
  sc[i] = A;
  bi[i] = b[c] - mean * A;
}

// ---------------- GN apply + LeakyReLU (layer 5_2): bf16 in, f32 out ----------------
__global__ __launch_bounds__(256) void k_apply52(const u16* __restrict__ h2,
    float* __restrict__ outp, const float* __restrict__ gsum,
    const float* __restrict__ g, const float* __restrict__ b) {
  int gid = blockIdx.x * 256 + threadIdx.x;          // grid 4096 -> 8 elems/thread
  size_t e = (size_t)gid * 8;
  int row = (int)(e >> 9);                           // Ctot = 512
  int c = (int)e & 511;
  int grp = c >> 5;
  float2 s = *(const float2*)(gsum + (size_t)((row >> 11)*16 + grp)*2);
  const float cnt = 65536.f;
  float mean = s.x / cnt, rstd = rsqrtf(s.y / cnt - mean*mean + 1e-5f);
  u16x8 v = *(const u16x8*)(h2 + e);
  float gv[8], bv[8];
  *(float4*)&gv[0] = *(const float4*)(g + c); *(float4*)&gv[4] = *(const float4*)(g + c + 4);
  *(float4*)&bv[0] = *(const float4*)(b + c); *(float4*)&bv[4] = *(const float4*)(b + c + 4);
  float h[8];
  #pragma unroll
  for (int q = 0; q < 8; ++q) {
    float xv = bf2f((u16)v[q]);
    float o = (xv - mean) * rstd * gv[q] + bv[q];
    h[q] = o > 0.f ? o : 0.2f * o;
  }
  *(float4*)(outp + e)     = make_float4(h[0], h[1], h[2], h[3]);
  *(float4*)(outp + e + 4) = make_float4(h[4], h[5], h[6], h[7]);
}

// ---------------- bf16 MFMA GEMM + fused GN stats (+ mono' store / A-transform) ----------------
// R9 structure (best measured): single-buffer 2-barrier, glds16 staging, scalar C stores.
template<int OUTF32, int MONO, int TRANSA>
__global__ __launch_bounds__(256) void k_gemm(const u16* __restrict__ A, int lda,
    const u16* __restrict__ Bw, int K, void* __restrict__ outp, int ldc,
    int CgShift, int NG, float* __restrict__ gsum,
    const float* __restrict__ ga, const float* __restrict__ gb, int Ca,
    const float* __restrict__ scA, const float* __restrict__ biA) {
  constexpr int BK = 64;
  __shared__ __align__(16) u16 As[128 * BK];
  __shared__ __align__(16) u16 Bs[128 * BK];
  __shared__ float colsum[128], colss[128];
  const int tid = threadIdx.x;
  const int wid = tid >> 6, lane = tid & 63;
  const int tileM = blockIdx.x * 128, tileN = blockIdx.y * 128;
  const int wm = wid >> 1, wn = wid & 1;
  const int lr = lane & 15, lk = (lane >> 4) * 8;
  const float* scb = TRANSA ? (scA + (size_t)(tileM >> 11) * 1024) : nullptr;
  const float* bib = TRANSA ? (biA + (size_t)(tileM >> 11) * 1024) : nullptr;
  f32x4 acc[4][4] = {};
  for (int k0 = 0; k0 < K; k0 += BK) {
    __syncthreads();
    #pragma unroll
    for (int i = 0; i < 4; ++i) {
      int flat = i * 256 + tid;
      int row = flat >> 3, ck = flat & 7;
      if (TRANSA) {
        int cbase = k0 + ck * 8;
        uint4 v = *(const uint4*)(A + (size_t)(tileM + row) * lda + cbase);
        float4 s0 = *(const float4*)(scb + cbase);
        float4 s1 = *(const float4*)(scb + cbase + 4);
        float4 b0 = *(const float4*)(bib + cbase);
        float4 b1 = *(const float4*)(bib + cbase + 4);
        float sc8[8] = {s0.x,s0.y,s0.z,s0.w,s1.x,s1.y,s1.z,s1.w};
        float bi8[8] = {b0.x,b0.y,b0.z,b0.w,b1.x,b1.y,b1.z,b1.w};
        u32 vv[4] = {v.x, v.y, v.z, v.w};
        u32 ov[4];
        #pragma unroll
        for (int q2 = 0; q2 < 4; ++q2) {
          float x0 = bf2f((u16)(vv[q2] & 0xFFFF));
          float x1 = bf2f((u16)(vv[q2] >> 16));
          float o0 = x0 * sc8[q2*2]   + bi8[q2*2];
          float o1 = x1 * sc8[q2*2+1] + bi8[q2*2+1];
          o0 = o0 > 0.f ? o0 : 0.2f * o0;
          o1 = o1 > 0.f ? o1 : 0.2f * o1;
          ov[q2] = (u32)f2bf(o0) | (((u32)f2bf(o1)) << 16);
        }
        *(uint4*)((char*)As + flat * 16) = make_uint4(ov[0], ov[1], ov[2], ov[3]);
      } else {
        glds16(A + (size_t)(tileM + row) * lda + (k0 + ck * 8), (char*)As + flat * 16);
      }
    }
    #pragma unroll
    for (int i = 0; i < 4; ++i) {
      int flat = i * 256 + tid;
      int row = flat >> 3, ck = flat & 7;
      glds16(Bw + (size_t)(tileN + row) * K + (k0 + ck * 8), (char*)Bs + flat * 16);
    }
    __syncthreads();
    #pragma unroll
    for (int ks = 0; ks < 2; ++ks) {
      bf16x8 af[4], bfr[4];
      #pragma unroll
      for (int i = 0; i < 4; ++i)
        af[i] = *(const bf16x8*)&As[(wm*64 + i*16 + lr) * BK + ks*32 + lk];
      #pragma unroll
      for (int j = 0; j < 4; ++j)
        bfr[j] = *(const bf16x8*)&Bs[(wn*64 + j*16 + lr) * BK + ks*32 + lk];
      #pragma unroll
      for (int i = 0; i < 4; ++i)
        #pragma unroll
        for (int j = 0; j < 4; ++j)
          acc[i][j] = __builtin_amdgcn_mfma_f32_16x16x32_bf16(af[i], bfr[j], acc[i][j], 0, 0, 0);
    }
  }
  const int orow0 = tileM + wm*64 + ((lane >> 4) * 4);
  const int ocol0 = tileN + wn*64 + lr;

  u16 flip[4] = {0,0,0,0};
  if (MONO) {
    #pragma unroll
    for (int j = 0; j < 4; ++j) {
      int colg = ocol0 + j*16;
      float gm = (colg < Ca) ? ga[colg] : gb[colg - Ca];
      flip[j] = (gm < 0.f) ? (u16)0xFFFF : (u16)0;
    }
  }

  float csum[4] = {0.f,0.f,0.f,0.f}, css[4] = {0.f,0.f,0.f,0.f};
  #pragma unroll
  for (int i = 0; i < 4; ++i)
    #pragma unroll
    for (int j = 0; j < 4; ++j)
      #pragma unroll
      for (int r = 0; r < 4; ++r) {
        int row = orow0 + i*16 + r;
        int col = ocol0 + j*16;
        float v = acc[i][j][r];
        csum[j] += v; css[j] += v*v;
        if (OUTF32) ((float*)outp)[(size_t)row * ldc + col] = v;
        else {
          u16 st = f2bf(v);
          if (MONO) st = (u16)(mono(st) ^ flip[j]);
          ((u16*)outp)[(size_t)row * ldc + col] = st;
        }
      }

  #pragma unroll
  for (int mask = 16; mask <= 32; mask <<= 1)
    #pragma unroll
    for (int j = 0; j < 4; ++j) {
      csum[j] += __shfl_xor(csum[j], mask, 64);
      css[j]  += __shfl_xor(css[j],  mask, 64);
    }
  if (tid < 128) { colsum[tid] = 0.f; colss[tid] = 0.f; }
  __syncthreads();
  if ((lane >> 4) == 0) {
    #pragma unroll
    for (int j = 0; j < 4; ++j) {
      int col = wn*64 + j*16 + lr;
      atomicAdd(&colsum[col], csum[j]);
      atomicAdd(&colss[col],  css[j]);
    }
  }
  __syncthreads();
  const int NGtile = 128 >> CgShift;
  if (tid < NGtile) {
    float s = 0.f, ss = 0.f;
    const int Cg = 1 << CgShift;
    for (int c0 = tid << CgShift; c0 < (tid << CgShift) + Cg; ++c0) { s += colsum[c0]; ss += colss[c0]; }
    int b = tileM >> 11;
    int gidx = (tileN >> CgShift) + tid;
    atomicAdd(&gsum[(size_t)(b*NG + gidx)*2],   s);
    atomicAdd(&gsum[(size_t)(b*NG + gidx)*2+1], ss);
  }
}

// ---------------- launch ----------------
extern "C" void kernel_launch(void* const* d_in, const int* in_sizes, int n_in,
                              void* d_out, int out_size, void* d_ws, size_t ws_size,
                              hipStream_t stream) {
  const float* x   = (const float*)d_in[0];
  const float* w1a = (const float*)d_in[1];
  const float* g1a = (const float*)d_in[2];
  const float* b1a = (const float*)d_in[3];
  const float* w1b = (const float*)d_in[4];
  const float* g1b = (const float*)d_in[5];
  const float* b1b = (const float*)d_in[6];
  const float* w2a = (const float*)d_in[7];
  const float* g2a = (const float*)d_in[8];
  const float* b2a = (const float*)d_in[9];
  const float* w2b = (const float*)d_in[10];
  const float* g2b = (const float*)d_in[11];
  const float* b2b = (const float*)d_in[12];
  const float* w3a = (const float*)d_in[13];
  const float* g3a = (const float*)d_in[14];
  const float* b3a = (const float*)d_in[15];
  const float* w3b = (const float*)d_in[16];
  const float* g3b = (const float*)d_in[17];
  const float* b3b = (const float*)d_in[18];
  const float* w4a = (const float*)d_in[19];
  const float* g4a = (const float*)d_in[20];
  const float* b4a = (const float*)d_in[21];
  const float* w4b = (const float*)d_in[22];
  const float* g4b = (const float*)d_in[23];
  const float* b4b = (const float*)d_in[24];
  const float* w51 = (const float*)d_in[25];
  const float* g51 = (const float*)d_in[26];
  const float* b51 = (const float*)d_in[27];
  const float* w52 = (const float*)d_in[28];
  const float* g52 = (const float*)d_in[29];
  const float* b52 = (const float*)d_in[30];

  char* ws = (char*)d_ws;
  int*    idxp   = (int*)   (ws + 0);               // 5,242,880 (dead after L4 gather)
  float4* c4     = (float4*)(ws + 5242880);         // 262,144
  u16*    wbf    = (u16*)   (ws + 5505024);         // 2,277,376
  float*  gsum   = (float*) (ws + 7782400);         // 8,192
  u16*    convAB = (u16*)   (ws + 7790592);         // 16,777,216 (dead after L4 gather)
  u16*    h1     = (u16*)   (ws + 24567808);        // 33,554,432
  u16*    xcat   = (u16*)   (ws + 58122240);        // 16,777,216
  // after L4 gather: sc51/bi51 live in idxp region; h2 (bf16 5_2 out) in convAB region
  float*  sc51   = (float*) (ws + 0);               // 32,768
  float*  bi51   = (float*) (ws + 32768);           // 32,768
  u16*    h2     = (u16*)   (ws + 7790592);         // 16,777,216 (16384*512*2)
  u16* wc2 = wbf, *wc3 = wbf + 8192, *wc4 = wbf + 24576;
  u16* w51b = wbf + 90112, *w52b = wbf + 614400;
  float* outf = (float*)d_out;
  float* gsL1 = gsum;        float* gsL2 = gsum + 256;  float* gsL3 = gsum + 512;
  float* gsL4 = gsum + 768;  float* gs51 = gsum + 1280; float* gs52 = gsum + 1536;

  k_pack_all<<<4448, 256, 0, stream>>>(x, c4, gsum, w2a, w2b, w3a, w3b, w4a, w4b,
                                       w51, w52, wbf);

  // knn (4096 blocks) + layer-1 conv (128 blocks) fused
  k_knn_conv1<<<4224, 256, 0, stream>>>(c4, idxp, x, w1a, w1b, g1a, g1b, convAB, gsL1);

  // layer 1 gather (+GN)
  k_gather<<<512, 256, 0, stream>>>(convAB, 128, 64, 3, 16, gsL1,
                                    g1a, b1a, g1b, b1b, idxp, 20, xcat, 0, 3);

  // layer 2
  k_gemm<0,1,0><<<dim3(128,1), 256, 0, stream>>>(xcat + 0, 512, wc2, 64, convAB, 128,
                                                 3, 16, gsL2, g2a, g2b, 64, nullptr, nullptr);
  k_gather<<<512, 256, 0, stream>>>(convAB, 128, 64, 3, 16, gsL2,
                                    g2a, b2a, g2b, b2b, idxp, 40, xcat, 64, 3);

  // layer 3
  k_gemm<0,1,0><<<dim3(128,2), 256, 0, stream>>>(xcat + 64, 512, wc3, 64, convAB, 256,
                                                 4, 16, gsL3, g3a, g3b, 128, nullptr, nullptr);
  k_gather<<<1024, 256, 0, stream>>>(convAB, 256, 128, 4, 16, gsL3,
                                     g3a, b3a, g3b, b3b, idxp, 60, xcat, 128, 4);

  // layer 4
  k_gemm<0,1,0><<<dim3(128,4), 256, 0, stream>>>(xcat + 128, 512, wc4, 128, convAB, 512,
                                                 4, 32, gsL4, g4a, g4b, 256, nullptr, nullptr);
  k_gather<<<2048, 256, 0, stream>>>(convAB, 512, 256, 4, 32, gsL4,
                                     g4a, b4a, g4b, b4b, idxp, 80, xcat, 256, 5);

  // layer 5_1 (512->1024): GEMM(raw out)+stats; GN folded into scale/bias tables
  k_gemm<0,0,0><<<dim3(128,8), 256, 0, stream>>>(xcat, 512, w51b, 512, h1, 1024,
                                                 6, 16, gs51, g51, g51, 1024, nullptr, nullptr);
  k_sb51<<<32, 256, 0, stream>>>(gs51, g51, b51, sc51, bi51);

  // layer 5_2 (1024->512): GEMM(bf16 out -> h2)+stats, fused A-transform (GN+LReLU of 5_1)
  k_gemm<0,0,1><<<dim3(128,4), 256, 0, stream>>>(h1, 1024, w52b, 1024, h2, 512,
                                                 5, 16, gs52, g52, g52, 512, sc51, bi51);
  // final GN apply: bf16 h2 -> f32 d_out
  k_apply52<<<4096, 256, 0, stream>>>(h2, outf, gs52, g52, b52);
}

// Round 18
// 243.808 us; speedup vs baseline: 1.1260x; 1.0030x over previous
//
#include <hip/hip_runtime.h>
#include <stdint.h>

typedef unsigned short u16;
typedef unsigned int u32;
typedef unsigned long long u64;
typedef __attribute__((ext_vector_type(8))) __bf16 bf16x8;
typedef __attribute__((ext_vector_type(8))) u16 u16x8;
typedef __attribute__((ext_vector_type(4))) float f32x4;

#define DEVI __device__ __forceinline__

DEVI u16 f2bf(float f) {                    // fp32 -> bf16 RNE
  u32 u = __float_as_uint(f);
  u += 0x7FFFu + ((u >> 16) & 1u);
  return (u16)(u >> 16);
}
DEVI float bf2f(u16 h) { return __uint_as_float(((u32)h) << 16); }
DEVI u16 mono(u16 b) {                      // order-isomorphic bf16 -> u16
  return (b & 0x8000u) ? (u16)~b : (u16)(b | 0x8000u);
}
DEVI u16 unmono(u16 t) {
  return (t & 0x8000u) ? (u16)(t ^ 0x8000u) : (u16)(~t);
}

DEVI void glds16(const void* g, void* l) {  // 16B-per-lane global->LDS DMA
  __builtin_amdgcn_global_load_lds((const __attribute__((address_space(1))) void*)g,
                                   (__attribute__((address_space(3))) void*)l, 16, 0, 0);
}

// ---------------- prep: weights->bf16, coords pack, gsum zero (merged) ----------------
__global__ void k_pack_all(const float* __restrict__ x, float4* __restrict__ c4,
                           float* __restrict__ gsum,
                           const float* __restrict__ w2a, const float* __restrict__ w2b,
                           const float* __restrict__ w3a, const float* __restrict__ w3b,
                           const float* __restrict__ w4a, const float* __restrict__ w4b,
                           const float* __restrict__ w51, const float* __restrict__ w52,
                           u16* __restrict__ wbf) {
  int g = blockIdx.x * 256 + threadIdx.x;          // grid 4448*256 = 1,138,688 exact
  if (g < 1792) gsum[g] = 0.f;
  if (g < 16384) {
    float x0 = x[g*3], x1 = x[g*3+1], x2 = x[g*3+2];
    float n = __fadd_rn(__fadd_rn(__fmul_rn(x0,x0), __fmul_rn(x1,x1)), __fmul_rn(x2,x2));
    c4[g] = make_float4(x0, x1, x2, n);
  }
  const float* s; int off;
  if      (g <    4096) { s = w2a; off = g; }
  else if (g <    8192) { s = w2b; off = g - 4096; }
  else if (g <   16384) { s = w3a; off = g - 8192; }
  else if (g <   24576) { s = w3b; off = g - 16384; }
  else if (g <   57344) { s = w4a; off = g - 24576; }
  else if (g <   90112) { s = w4b; off = g - 57344; }
  else if (g <  614400) { s = w51; off = g - 90112; }
  else                  { s = w52; off = g - 614400; }
  wbf[g] = f2bf(s[off]);
}

// ---------------- knn (blocks 0..4095) + layer-1 conv (blocks 4096..4223), fused ----------------
__global__ __launch_bounds__(256, 8) void k_knn_conv1(
    const float4* __restrict__ c4, int* __restrict__ idxp,
    const float* __restrict__ x,
    const float* __restrict__ w1a, const float* __restrict__ w1b,
    const float* __restrict__ g1a, const float* __restrict__ g1b,
    u16* __restrict__ convout, float* __restrict__ gsum) {
  __shared__ u64 cand[4][128];
  __shared__ float xs[384];
  __shared__ float colsum[128], colss[128];
  const int tid = threadIdx.x;

  if (blockIdx.x >= 4096) {
    // ---------- conv1 path ----------
    const int P0 = (blockIdx.x - 4096) * 128;
    for (int i = tid; i < 384; i += 256) xs[i] = x[P0*3 + i];
    if (tid < 128) { colsum[tid] = 0.f; colss[tid] = 0.f; }
    __syncthreads();

    const int c = tid & 127;
    const int half = tid >> 7;
    const float* w = (c < 64) ? (w1a + 3*c) : (w1b + 3*(c-64));
    float wx = w[0], wy = w[1], wz = w[2];
    float gam = (c < 64) ? g1a[c] : g1b[c-64];
    u16 flip = (gam < 0.f) ? (u16)0xFFFF : (u16)0;

    float s = 0.f, ss = 0.f;
    #pragma unroll 4
    for (int p_ = 0; p_ < 64; ++p_) {
      int p = (half << 6) + p_;
      float h = wx*xs[p*3] + wy*xs[p*3+1] + wz*xs[p*3+2];
      s += h; ss += h*h;
      convout[(size_t)(P0 + p)*128 + c] = (u16)(mono(f2bf(h)) ^ flip);
    }
    atomicAdd(&colsum[c], s);
    atomicAdd(&colss[c], ss);
    __syncthreads();
    if (tid < 16) {
      float gs = 0.f, gss = 0.f;
      #pragma unroll
      for (int q = 0; q < 8; ++q) { gs += colsum[tid*8+q]; gss += colss[tid*8+q]; }
      int b = P0 >> 11;
      atomicAdd(&gsum[(b*16 + tid)*2],   gs);
      atomicAdd(&gsum[(b*16 + tid)*2+1], gss);
    }
    return;
  }

  // ---------- knn path ----------
  const int wid = tid >> 6;
  const int lane = tid & 63;
  const int batch = blockIdx.x & 7;
  const int qib = (blockIdx.x >> 3) * 4 + wid;      // query within batch
  const int blk = (batch << 11) + qib;
  const float4* cb = c4 + (batch << 11);
  const float4 q = cb[qib];

  u32 key[32];
  #pragma unroll
  for (int s = 0; s < 32; ++s) {
    float4 c = cb[s*64 + lane];
    float inner = __fadd_rn(__fadd_rn(__fmul_rn(q.x,c.x), __fmul_rn(q.y,c.y)), __fmul_rn(q.z,c.z));
    float pd = __fsub_rn(__fsub_rn(__fmul_rn(2.0f, inner), q.w), c.w);
    u32 bits = __float_as_uint(pd);
    key[s] = (bits & 0x80000000u) ? ~bits : (bits | 0x80000000u);
  }

  // wave-max of non-self keys (self key is exactly 0x80000000; excluded by value)
  u32 Mh = 0;
  #pragma unroll
  for (int s = 0; s < 32; ++s) {
    u32 kk = key[s];
    if (kk != 0x80000000u && kk > Mh) Mh = kk;
  }
  #pragma unroll
  for (int m = 32; m; m >>= 1) {
    u32 o = __shfl_xor(Mh, m, 64);
    if (o > Mh) Mh = o;
  }

  // radix bisect with prefix skip (invariant incl. bit31; see R17 note)
  u32 T = 0;
  bool onpfx = ((Mh & 0x80000000u) == 0u);
  for (int bit = 30; bit >= 0; --bit) {
    if (onpfx && !((Mh >> bit) & 1u)) continue;
    u32 Tc = T | (1u << bit);
    int c = 0;
    #pragma unroll
    for (int s = 0; s < 32; ++s)
      c += __popcll(__ballot(key[s] >= Tc));
    if (c >= 80) { T = Tc; if (c <= 128) break; }
    else onpfx = false;
  }

  cand[wid][lane] = 0ull;
  cand[wid][lane + 64] = 0ull;
  asm volatile("s_waitcnt lgkmcnt(0)" ::: "memory");

  const u64 below = (lane == 0) ? 0ull : (~0ull >> (64 - lane));
  int base = 0;
  #pragma unroll
  for (int s = 0; s < 32; ++s) {
    u64 msk = __ballot(key[s] >= T);
    if (key[s] >= T) {
      int pos = base + (int)__popcll(msk & below);
      if (pos < 128)
        cand[wid][pos] = (((u64)key[s]) << 32) | (u32)(2047 - (s*64 + lane));
    }
    base += (int)__popcll(msk);
  }
  asm volatile("s_waitcnt lgkmcnt(0)" ::: "memory");

  u64 v0 = cand[wid][lane];
  u64 v1 = cand[wid][lane + 64];
  #pragma unroll
  for (int k2 = 2; k2 <= 128; k2 <<= 1) {
    #pragma unroll
    for (int j = k2 >> 1; j > 0; j >>= 1) {
      if (j == 64) {                                // cross-slot, in-lane
        u64 mx = v0 > v1 ? v0 : v1;
        u64 mn = v0 > v1 ? v1 : v0;
        v0 = mx; v1 = mn;
      } else {
        u64 p0 = __shfl_xor(v0, j, 64);
        u64 p1 = __shfl_xor(v1, j, 64);
        bool lowlane = ((lane & j) == 0);
        bool d0 = ((lane & k2) == 0);
        bool d1 = (((lane + 64) & k2) == 0);
        bool wm0 = (d0 == lowlane);
        bool wm1 = (d1 == lowlane);
        u64 mx0 = v0 > p0 ? v0 : p0, mn0 = v0 > p0 ? p0 : v0;
        u64 mx1 = v1 > p1 ? v1 : p1, mn1 = v1 > p1 ? p1 : v1;
        v0 = wm0 ? mx0 : mn0;
        v1 = wm1 ? mx1 : mn1;
      }
    }
  }

  idxp[(size_t)blk*80 + lane] = 2047 - (int)(u32)v0;
  if (lane < 16) idxp[(size_t)blk*80 + 64 + lane] = 2047 - (int)(u32)v1;
}

// ---------------- fused gather-max + GroupNorm + LeakyReLU + add-fb ----------------
__global__ __launch_bounds__(256) void k_gather(const u16* __restrict__ conv, int Ctot, int Ca,
    int CgShift, int NG, const float* __restrict__ gsum,
    const float* __restrict__ ga, const float* __restrict__ ba,
    const float* __restrict__ gb, const float* __restrict__ bb,
    const int* __restrict__ idxp, int k,
    u16* __restrict__ xcat, int outOff, int lppShift) {
  const int batch = blockIdx.x & 7;
  const int blkin = blockIdx.x >> 3;
  const int lgid = blkin * 256 + threadIdx.x;
  const int p_in = lgid >> lppShift;
  const int c8 = (lgid & ((1 << lppShift) - 1)) * 8;
  const int p = (batch << 11) + p_in;
  const int* irow = idxp + (size_t)p * 80;
  const u16* cb = conv + ((size_t)(batch << 11)) * Ctot + c8;

  const int gia = c8 >> CgShift;
  const int gib = (Ca + c8) >> CgShift;
  const float cnt = (float)(2048 << CgShift);
  float2 sa = *(const float2*)(gsum + (size_t)(batch*NG + gia)*2);
  float2 sb = *(const float2*)(gsum + (size_t)(batch*NG + gib)*2);
  float meanA = sa.x / cnt, rstdA = rsqrtf(sa.y / cnt - meanA*meanA + 1e-5f);
  float meanB = sb.x / cnt, rstdB = rsqrtf(sb.y / cnt - meanB*meanB + 1e-5f);

  float gav[8], bav[8], gbv[8], bbv[8];
  *(float4*)&gav[0] = *(const float4*)(ga + c8); *(float4*)&gav[4] = *(const float4*)(ga + c8 + 4);
  *(float4*)&bav[0] = *(const float4*)(ba + c8); *(float4*)&bav[4] = *(const float4*)(ba + c8 + 4);
  *(float4*)&gbv[0] = *(const float4*)(gb + c8); *(float4*)&gbv[4] = *(const float4*)(gb + c8 + 4);
  *(float4*)&bbv[0] = *(const float4*)(bb + c8); *(float4*)&bbv[4] = *(const float4*)(bb + c8 + 4);

  u16x8 fbv = *(const u16x8*)(conv + (size_t)p * Ctot + Ca + c8);

  u16x8 m8 = (u16x8)(u16)0;
  for (int j0 = 0; j0 < k; j0 += 4) {
    int4 mi4 = *(const int4*)(irow + j0);
    int mis[4] = {mi4.x, mi4.y, mi4.z, mi4.w};
    u16x8 rows[4];
    #pragma unroll
    for (int u = 0; u < 4; ++u)
      rows[u] = *(const u16x8*)(cb + (size_t)mis[u] * Ctot);
    #pragma unroll
    for (int u = 0; u < 4; ++u)
      m8 = __builtin_elementwise_max(m8, rows[u]);   // v_pk_max_u16
  }

  u16 ov[8];
  #pragma unroll
  for (int q = 0; q < 8; ++q) {
    u16 fA = (gav[q] < 0.f) ? (u16)0xFFFF : (u16)0;
    u16 fB = (gbv[q] < 0.f) ? (u16)0xFFFF : (u16)0;
    float xa = bf2f(unmono((u16)((u16)m8[q] ^ fA)));
    float ha = (xa - meanA) * rstdA * gav[q] + bav[q];
    ha = ha > 0.f ? ha : 0.2f * ha;
    float xb = bf2f(unmono((u16)((u16)fbv[q] ^ fB)));
    float hb = (xb - meanB) * rstdB * gbv[q] + bbv[q];
    hb = hb > 0.f ? hb : 0.2f * hb;
    ov[q] = f2bf(ha + hb);
  }
  *(u16x8*)(xcat + (size_t)p * 512 + outOff + c8) = *(u16x8*)ov;
}

// ---------------- scale/bias tables for layer 5_1 GN (replaces apply51 pass) ----------------
__global__ void k_sb51(const float* __restrict__ gsum, const float* __restrict__ g,
                       const float* __restrict__ b, float* __restrict__ sc,
                       float* __restrict__ bi) {
  int i = blockIdx.x * 256 + threadIdx.x;            // < 8192 (8 batches x 1024 ch)
  int bb = i >> 10, c = i & 1023;
  int grp = c >> 6;
  float2 s = *(const float2*)(gsum + (size_t)(bb*16 + grp)*2);
  float mean = s.x / 131072.f;
  float rstd = rsqrtf(s.y / 131072.f - mean*mean + 1e-5f);
  float A = rstd * g[c];
  sc[i] = A;
  bi[i] = b[c] - mean * A;
}

// ---------------- GN apply + LeakyReLU (layer 5_2): bf16 in, f32 out ----------------
__global__ __launch_bounds__(256) void k_apply52(const u16* __restrict__ h2,
    float* __restrict__ outp, const float* __restrict__ gsum,
    const float* __restrict__ g, const float* __restrict__ b) {
  int gid = blockIdx.x * 256 + threadIdx.x;          // grid 4096 -> 8 elems/thread
  size_t e = (size_t)gid * 8;
  int row = (int)(e >> 9);                           // Ctot = 512
  int c = (int)e & 511;
  int grp = c >> 5;
  float2 s = *(const float2*)(gsum + (size_t)((row >> 11)*16 + grp)*2);
  const float cnt = 65536.f;
  float mean = s.x / cnt, rstd = rsqrtf(s.y / cnt - mean*mean + 1e-5f);
  u16x8 v = *(const u16x8*)(h2 + e);
  float gv[8], bv[8];
  *(float4*)&gv[0] = *(const float4*)(g + c); *(float4*)&gv[4] = *(const float4*)(g + c + 4);
  *(float4*)&bv[0] = *(const float4*)(b + c); *(float4*)&bv[4] = *(const float4*)(b + c + 4);
  float h[8];
  #pragma unroll
  for (int q = 0; q < 8; ++q) {
    float xv = bf2f((u16)v[q]);
    float o = (xv - mean) * rstd * gv[q] + bv[q];
    h[q] = o > 0.f ? o : 0.2f * o;
  }
  *(float4*)(outp + e)     = make_float4(h[0], h[1], h[2], h[3]);
  *(float4*)(outp + e + 4) = make_float4(h[4], h[5], h[6], h[7]);
}

// ---------------- bf16 MFMA GEMM + fused GN stats + mono' store (128x128 tile) ----------------
template<int OUTF32, int MONO, int TRANSA>
__global__ __launch_bounds__(256) void k_gemm(const u16* __restrict__ A, int lda,
    const u16* __restrict__ Bw, int K, void* __restrict__ outp, int ldc,
    int CgShift, int NG, float* __restrict__ gsum,
    const float* __restrict__ ga, const float* __restrict__ gb, int Ca,
    const float* __restrict__ scA, const float* __restrict__ biA) {
  constexpr int BK = 64;
  __shared__ __align__(16) u16 As[128 * BK];
  __shared__ __align__(16) u16 Bs[128 * BK];
  __shared__ float colsum[128], colss[128];
  const int tid = threadIdx.x;
  const int wid = tid >> 6, lane = tid & 63;
  const int tileM = blockIdx.x * 128, tileN = blockIdx.y * 128;
  const int wm = wid >> 1, wn = wid & 1;
  const int lr = lane & 15, lk = (lane >> 4) * 8;
  const float* scb = TRANSA ? (scA + (size_t)(tileM >> 11) * 1024) : nullptr;
  const float* bib = TRANSA ? (biA + (size_t)(tileM >> 11) * 1024) : nullptr;
  f32x4 acc[4][4] = {};
  for (int k0 = 0; k0 < K; k0 += BK) {
    __syncthreads();
    #pragma unroll
    for (int i = 0; i < 4; ++i) {
      int flat = i * 256 + tid;
      int row = flat >> 3, ck = flat & 7;
      if (TRANSA) {
        int cbase = k0 + ck * 8;
        uint4 v = *(const uint4*)(A + (size_t)(tileM + row) * lda + cbase);
        float4 s0 = *(const float4*)(scb + cbase);
        float4 s1 = *(const float4*)(scb + cbase + 4);
        float4 b0 = *(const float4*)(bib + cbase);
        float4 b1 = *(const float4*)(bib + cbase + 4);
        float sc8[8] = {s0.x,s0.y,s0.z,s0.w,s1.x,s1.y,s1.z,s1.w};
        float bi8[8] = {b0.x,b0.y,b0.z,b0.w,b1.x,b1.y,b1.z,b1.w};
        u32 vv[4] = {v.x, v.y, v.z, v.w};
        u32 ov[4];
        #pragma unroll
        for (int q2 = 0; q2 < 4; ++q2) {
          float x0 = bf2f((u16)(vv[q2] & 0xFFFF));
          float x1 = bf2f((u16)(vv[q2] >> 16));
          float o0 = x0 * sc8[q2*2]   + bi8[q2*2];
          float o1 = x1 * sc8[q2*2+1] + bi8[q2*2+1];
          o0 = o0 > 0.f ? o0 : 0.2f * o0;
          o1 = o1 > 0.f ? o1 : 0.2f * o1;
          ov[q2] = (u32)f2bf(o0) | (((u32)f2bf(o1)) << 16);
        }
        *(uint4*)((char*)As + flat * 16) = make_uint4(ov[0], ov[1], ov[2], ov[3]);
      } else {
        glds16(A + (size_t)(tileM + row) * lda + (k0 + ck * 8), (char*)As + flat * 16);
      }
    }
    #pragma unroll
    for (int i = 0; i < 4; ++i) {
      int flat = i * 256 + tid;
      int row = flat >> 3, ck = flat & 7;
      glds16(Bw + (size_t)(tileN + row) * K + (k0 + ck * 8), (char*)Bs + flat * 16);
    }
    __syncthreads();
    #pragma unroll
    for (int ks = 0; ks < 2; ++ks) {
      bf16x8 af[4], bfr[4];
      #pragma unroll
      for (int i = 0; i < 4; ++i)
        af[i] = *(const bf16x8*)&As[(wm*64 + i*16 + lr) * BK + ks*32 + lk];
      #pragma unroll
      for (int j = 0; j < 4; ++j)
        bfr[j] = *(const bf16x8*)&Bs[(wn*64 + j*16 + lr) * BK + ks*32 + lk];
      #pragma unroll
      for (int i = 0; i < 4; ++i)
        #pragma unroll
        for (int j = 0; j < 4; ++j)
          acc[i][j] = __builtin_amdgcn_mfma_f32_16x16x32_bf16(af[i], bfr[j], acc[i][j], 0, 0, 0);
    }
  }
  const int orow0 = tileM + wm*64 + ((lane >> 4) * 4);
  const int ocol0 = tileN + wn*64 + lr;

  u16 flip[4] = {0,0,0,0};
  if (MONO) {
    #pragma unroll
    for (int j = 0; j < 4; ++j) {
      int colg = ocol0 + j*16;
      float gm = (colg < Ca) ? ga[colg] : gb[colg - Ca];
      flip[j] = (gm < 0.f) ? (u16)0xFFFF : (u16)0;
    }
  }

  float csum[4] = {0.f,0.f,0.f,0.f}, css[4] = {0.f,0.f,0.f,0.f};
  #pragma unroll
  for (int i = 0; i < 4; ++i)
    #pragma unroll
    for (int j = 0; j < 4; ++j)
      #pragma unroll
      for (int r = 0; r < 4; ++r) {
        int row = orow0 + i*16 + r;
        int col = ocol0 + j*16;
        float v = acc[i][j][r];
        csum[j] += v; css[j] += v*v;
        if (OUTF32) ((float*)outp)[(size_t)row * ldc + col] = v;
        else {
          u16 st = f2bf(v);
          if (MONO) st = (u16)(mono(st) ^ flip[j]);
          ((u16*)outp)[(size_t)row * ldc + col] = st;
        }
      }

  #pragma unroll
  for (int mask = 16; mask <= 32; mask <<= 1)
    #pragma unroll
    for (int j = 0; j < 4; ++j) {
      csum[j] += __shfl_xor(csum[j], mask, 64);
      css[j]  += __shfl_xor(css[j],  mask, 64);
    }
  if (tid < 128) { colsum[tid] = 0.f; colss[tid] = 0.f; }
  __syncthreads();
  if ((lane >> 4) == 0) {
    #pragma unroll
    for (int j = 0; j < 4; ++j) {
      int col = wn*64 + j*16 + lr;
      atomicAdd(&colsum[col], csum[j]);
      atomicAdd(&colss[col],  css[j]);
    }
  }
  __syncthreads();
  const int NGtile = 128 >> CgShift;
  if (tid < NGtile) {
    float s = 0.f, ss = 0.f;
    const int Cg = 1 << CgShift;
    for (int c0 = tid << CgShift; c0 < (tid << CgShift) + Cg; ++c0) { s += colsum[c0]; ss += colss[c0]; }
    int b = tileM >> 11;
    int gidx = (tileN >> CgShift) + tid;
    atomicAdd(&gsum[(size_t)(b*NG + gidx)*2],   s);
    atomicAdd(&gsum[(size_t)(b*NG + gidx)*2+1], ss);
  }
}

// ---------------- 64x128-tile GEMM (R14-verified) — for small L2/L3 gemms only ----------------
// 2x blocks -> full 256-CU coverage where the 128^2 grid left half the chip idle.
template<int MONO>
__global__ __launch_bounds__(256, 6) void k_gemm64(const u16* __restrict__ A, int lda,
    const u16* __restrict__ Bw, int K, u16* __restrict__ outp, int ldc,
    int CgShift, int NG, float* __restrict__ gsum,
    const float* __restrict__ ga, const float* __restrict__ gb, int Ca) {
  constexpr int BK = 64;
  __shared__ __align__(16) u16 As[64 * BK];         // 8 KB
  __shared__ __align__(16) u16 Bs[128 * BK];        // 16 KB
  __shared__ float colsum[128], colss[128];
  const int tid = threadIdx.x;
  const int wid = tid >> 6, lane = tid & 63;
  const int tileM = blockIdx.x * 64, tileN = blockIdx.y * 128;
  const int wn = wid;                               // 4 waves: cols wn*32..wn*32+31
  const int lr = lane & 15, lk = (lane >> 4) * 8;

  f32x4 acc[4][2] = {};
  for (int k0 = 0; k0 < K; k0 += BK) {
    __syncthreads();
    #pragma unroll
    for (int i = 0; i < 2; ++i) {                   // A tile: 64x64 u16 = 512 chunks
      int flat = i * 256 + tid;
      int row = flat >> 3, ck = flat & 7;
      glds16(A + (size_t)(tileM + row) * lda + (k0 + ck * 8), (char*)As + flat * 16);
    }
    #pragma unroll
    for (int i = 0; i < 4; ++i) {                   // B tile: 128x64 u16 = 1024 chunks
      int flat = i * 256 + tid;
      int row = flat >> 3, ck = flat & 7;
      glds16(Bw + (size_t)(tileN + row) * K + (k0 + ck * 8), (char*)Bs + flat * 16);
    }
    __syncthreads();
    #pragma unroll
    for (int ks = 0; ks < 2; ++ks) {
      bf16x8 af[4], bfr[2];
      #pragma unroll
      for (int i = 0; i < 4; ++i)
        af[i] = *(const bf16x8*)&As[(i*16 + lr) * BK + ks*32 + lk];
      #pragma unroll
      for (int j = 0; j < 2; ++j)
        bfr[j] = *(const bf16x8*)&Bs[(wn*32 + j*16 + lr) * BK + ks*32 + lk];
      #pragma unroll
      for (int i = 0; i < 4; ++i)
        #pragma unroll
        for (int j = 0; j < 2; ++j)
          acc[i][j] = __builtin_amdgcn_mfma_f32_16x16x32_bf16(af[i], bfr[j], acc[i][j], 0, 0, 0);
    }
  }

  const int orow0 = tileM + ((lane >> 4) * 4);
  const int ocol0 = tileN + wn*32 + lr;

  u16 flip[2] = {0,0};
  if (MONO) {
    #pragma unroll
    for (int j = 0; j < 2; ++j) {
      int colg = ocol0 + j*16;
      float gm = (colg < Ca) ? ga[colg] : gb[colg - Ca];
      flip[j] = (gm < 0.f) ? (u16)0xFFFF : (u16)0;
    }
  }

  float csum[2] = {0.f,0.f}, css[2] = {0.f,0.f};
  #pragma unroll
  for (int i = 0; i < 4; ++i)
    #pragma unroll
    for (int j = 0; j < 2; ++j)
      #pragma unroll
      for (int r = 0; r < 4; ++r) {
        int row = orow0 + i*16 + r;
        int col = ocol0 + j*16;
        float v = acc[i][j][r];
        csum[j] += v; css[j] += v*v;
        u16 st = f2bf(v);
        if (MONO) st = (u16)(mono(st) ^ flip[j]);
        outp[(size_t)row * ldc + col] = st;
      }

  #pragma unroll
  for (int mask = 16; mask <= 32; mask <<= 1)
    #pragma unroll
    for (int j = 0; j < 2; ++j) {
      csum[j] += __shfl_xor(csum[j], mask, 64);
      css[j]  += __shfl_xor(css[j],  mask, 64);
    }
  if (tid < 128) { colsum[tid] = 0.f; colss[tid] = 0.f; }
  __syncthreads();
  if ((lane >> 4) == 0) {
    #pragma unroll
    for (int j = 0; j < 2; ++j) {
      int col = wn*32 + j*16 + lr;
      atomicAdd(&colsum[col], csum[j]);
      atomicAdd(&colss[col],  css[j]);
    }
  }
  __syncthreads();
  const int NGtile = 128 >> CgShift;
  if (tid < NGtile) {
    float s = 0.f, ss = 0.f;
    const int Cg = 1 << CgShift;
    for (int c0 = tid << CgShift; c0 < (tid << CgShift) + Cg; ++c0) { s += colsum[c0]; ss += colss[c0]; }
    int b = tileM >> 11;
    int gidx = (tileN >> CgShift) + tid;
    atomicAdd(&gsum[(size_t)(b*NG + gidx)*2],   s);
    atomicAdd(&gsum[(size_t)(b*NG + gidx)*2+1], ss);
  }
}

// ---------------- launch ----------------
extern "C" void kernel_launch(void* const* d_in, const int* in_sizes, int n_in,
                              void* d_out, int out_size, void* d_ws, size_t ws_size,
                              hipStream_t stream) {
  const float* x   = (const float*)d_in[0];
  const float* w1a = (const float*)d_in[1];
  const float* g1a = (const float*)d_in[2];
  const float* b1a = (const float*)d_in[3];
  const float* w1b = (const float*)d_in[4];
  const float* g1b = (const float*)d_in[5];
  const float* b1b = (const float*)d_in[6];
  const float* w2a = (const float*)d_in[7];
  const float* g2a = (const float*)d_in[8];
  const float* b2a = (const float*)d_in[9];
  const float* w2b = (const float*)d_in[10];
  const float* g2b = (const float*)d_in[11];
  const float* b2b = (const float*)d_in[12];
  const float* w3a = (const float*)d_in[13];
  const float* g3a = (const float*)d_in[14];
  const float* b3a = (const float*)d_in[15];
  const float* w3b = (const float*)d_in[16];
  const float* g3b = (const float*)d_in[17];
  const float* b3b = (const float*)d_in[18];
  const float* w4a = (const float*)d_in[19];
  const float* g4a = (const float*)d_in[20];
  const float* b4a = (const float*)d_in[21];
  const float* w4b = (const float*)d_in[22];
  const float* g4b = (const float*)d_in[23];
  const float* b4b = (const float*)d_in[24];
  const float* w51 = (const float*)d_in[25];
  const float* g51 = (const float*)d_in[26];
  const float* b51 = (const float*)d_in[27];
  const float* w52 = (const float*)d_in[28];
  const float* g52 = (const float*)d_in[29];
  const float* b52 = (const float*)d_in[30];

  char* ws = (char*)d_ws;
  int*    idxp   = (int*)   (ws + 0);               // 5,242,880 (dead after L4 gather)
  float4* c4     = (float4*)(ws + 5242880);         // 262,144
  u16*    wbf    = (u16*)   (ws + 5505024);         // 2,277,376
  float*  gsum   = (float*) (ws + 7782400);         // 8,192
  u16*    convAB = (u16*)   (ws + 7790592);         // 16,777,216 (dead after L4 gather)
  u16*    h1     = (u16*)   (ws + 24567808);        // 33,554,432
  u16*    xcat   = (u16*)   (ws + 58122240);        // 16,777,216
  // after L4 gather: sc51/bi51 live in idxp region; h2 (bf16 5_2 out) in convAB region
  float*  sc51   = (float*) (ws + 0);               // 32,768
  float*  bi51   = (float*) (ws + 32768);           // 32,768
  u16*    h2     = (u16*)   (ws + 7790592);         // 16,777,216 (16384*512*2)
  u16* wc2 = wbf, *wc3 = wbf + 8192, *wc4 = wbf + 24576;
  u16* w51b = wbf + 90112, *w52b = wbf + 614400;
  float* outf = (float*)d_out;
  float* gsL1 = gsum;        float* gsL2 = gsum + 256;  float* gsL3 = gsum + 512;
  float* gsL4 = gsum + 768;  float* gs51 = gsum + 1280; float* gs52 = gsum + 1536;

  k_pack_all<<<4448, 256, 0, stream>>>(x, c4, gsum, w2a, w2b, w3a, w3b, w4a, w4b,
                                       w51, w52, wbf);

  // knn (4096 blocks) + layer-1 conv (128 blocks) fused
  k_knn_conv1<<<4224, 256, 0, stream>>>(c4, idxp, x, w1a, w1b, g1a, g1b, convAB, gsL1);

  // layer 1 gather (+GN)
  k_gather<<<512, 256, 0, stream>>>(convAB, 128, 64, 3, 16, gsL1,
                                    g1a, b1a, g1b, b1b, idxp, 20, xcat, 0, 3);

  // layer 2 (small gemm: 64-tile, 256 blocks = full chip)
  k_gemm64<1><<<dim3(256,1), 256, 0, stream>>>(xcat + 0, 512, wc2, 64, convAB, 128,
                                               3, 16, gsL2, g2a, g2b, 64);
  k_gather<<<512, 256, 0, stream>>>(convAB, 128, 64, 3, 16, gsL2,
                                    g2a, b2a, g2b, b2b, idxp, 40, xcat, 64, 3);

  // layer 3 (small gemm: 64-tile, 512 blocks)
  k_gemm64<1><<<dim3(256,2), 256, 0, stream>>>(xcat + 64, 512, wc3, 64, convAB, 256,
                                               4, 16, gsL3, g3a, g3b, 128);
  k_gather<<<1024, 256, 0, stream>>>(convAB, 256, 128, 4, 16, gsL3,
                                     g3a, b3a, g3b, b3b, idxp, 60, xcat, 128, 4);

  // layer 4 (128^2 tile — best measured for the big gemms)
  k_gemm<0,1,0><<<dim3(128,4), 256, 0, stream>>>(xcat + 128, 512, wc4, 128, convAB, 512,
                                                 4, 32, gsL4, g4a, g4b, 256, nullptr, nullptr);
  k_gather<<<2048, 256, 0, stream>>>(convAB, 512, 256, 4, 32, gsL4,
                                     g4a, b4a, g4b, b4b, idxp, 80, xcat, 256, 5);

  // layer 5_1 (512->1024): GEMM(raw out)+stats; GN folded into scale/bias tables
  k_gemm<0,0,0><<<dim3(128,8), 256, 0, stream>>>(xcat, 512, w51b, 512, h1, 1024,
                                                 6, 16, gs51, g51, g51, 1024, nullptr, nullptr);
  k_sb51<<<32, 256, 0, stream>>>(gs51, g51, b51, sc51, bi51);

  // layer 5_2 (1024->512): GEMM(bf16 out -> h2)+stats, fused A-transform (GN+LReLU of 5_1)
  k_gemm<0,0,1><<<dim3(128,4), 256, 0, stream>>>(h1, 1024, w52b, 1024, h2, 512,
                                                 5, 16, gs52, g52, g52, 512, sc51, bi51);
  // final GN apply: bf16 h2 -> f32 d_out
  k_apply52<<<4096, 256, 0, stream>>>(h2, outf, gs52, g52, b52);
}

// Round 19
// 241.637 us; speedup vs baseline: 1.1361x; 1.0090x over previous
//
#include <hip/hip_runtime.h>
#include <stdint.h>

typedef unsigned short u16;
typedef unsigned int u32;
typedef unsigned long long u64;
typedef __attribute__((ext_vector_type(8))) __bf16 bf16x8;
typedef __attribute__((ext_vector_type(8))) u16 u16x8;
typedef __attribute__((ext_vector_type(4))) float f32x4;

#define DEVI __device__ __forceinline__

DEVI u16 f2bf(float f) {                    // fp32 -> bf16 RNE
  u32 u = __float_as_uint(f);
  u += 0x7FFFu + ((u >> 16) & 1u);
  return (u16)(u >> 16);
}
DEVI float bf2f(u16 h) { return __uint_as_float(((u32)h) << 16); }
DEVI u16 mono(u16 b) {                      // order-isomorphic bf16 -> u16
  return (b & 0x8000u) ? (u16)~b : (u16)(b | 0x8000u);
}
DEVI u16 unmono(u16 t) {
  return (t & 0x8000u) ? (u16)(t ^ 0x8000u) : (u16)(~t);
}

DEVI void glds16(const void* g, void* l) {  // 16B-per-lane global->LDS DMA
  __builtin_amdgcn_global_load_lds((const __attribute__((address_space(1))) void*)g,
                                   (__attribute__((address_space(3))) void*)l, 16, 0, 0);
}

// ---------------- prep: weights->bf16, coords pack, gsum zero (merged) ----------------
__global__ void k_pack_all(const float* __restrict__ x, float4* __restrict__ c4,
                           float* __restrict__ gsum,
                           const float* __restrict__ w2a, const float* __restrict__ w2b,
                           const float* __restrict__ w3a, const float* __restrict__ w3b,
                           const float* __restrict__ w4a, const float* __restrict__ w4b,
                           const float* __restrict__ w51, const float* __restrict__ w52,
                           u16* __restrict__ wbf) {
  int g = blockIdx.x * 256 + threadIdx.x;          // grid 4448*256 = 1,138,688 exact
  if (g < 1792) gsum[g] = 0.f;
  if (g < 16384) {
    float x0 = x[g*3], x1 = x[g*3+1], x2 = x[g*3+2];
    float n = __fadd_rn(__fadd_rn(__fmul_rn(x0,x0), __fmul_rn(x1,x1)), __fmul_rn(x2,x2));
    c4[g] = make_float4(x0, x1, x2, n);
  }
  const float* s; int off;
  if      (g <    4096) { s = w2a; off = g; }
  else if (g <    8192) { s = w2b; off = g - 4096; }
  else if (g <   16384) { s = w3a; off = g - 8192; }
  else if (g <   24576) { s = w3b; off = g - 16384; }
  else if (g <   57344) { s = w4a; off = g - 24576; }
  else if (g <   90112) { s = w4b; off = g - 57344; }
  else if (g <  614400) { s = w51; off = g - 90112; }
  else                  { s = w52; off = g - 614400; }
  wbf[g] = f2bf(s[off]);
}

// ---------------- knn (blocks 0..4095) + layer-1 conv (blocks 4096..4223), fused ----------------
__global__ __launch_bounds__(256, 8) void k_knn_conv1(
    const float4* __restrict__ c4, int* __restrict__ idxp,
    const float* __restrict__ x,
    const float* __restrict__ w1a, const float* __restrict__ w1b,
    const float* __restrict__ g1a, const float* __restrict__ g1b,
    u16* __restrict__ convout, float* __restrict__ gsum) {
  __shared__ u64 cand[4][128];
  __shared__ float xs[384];
  __shared__ float colsum[128], colss[128];
  const int tid = threadIdx.x;

  if (blockIdx.x >= 4096) {
    // ---------- conv1 path ----------
    const int P0 = (blockIdx.x - 4096) * 128;
    for (int i = tid; i < 384; i += 256) xs[i] = x[P0*3 + i];
    if (tid < 128) { colsum[tid] = 0.f; colss[tid] = 0.f; }
    __syncthreads();

    const int c = tid & 127;
    const int half = tid >> 7;
    const float* w = (c < 64) ? (w1a + 3*c) : (w1b + 3*(c-64));
    float wx = w[0], wy = w[1], wz = w[2];
    float gam = (c < 64) ? g1a[c] : g1b[c-64];
    u16 flip = (gam < 0.f) ? (u16)0xFFFF : (u16)0;

    float s = 0.f, ss = 0.f;
    #pragma unroll 4
    for (int p_ = 0; p_ < 64; ++p_) {
      int p = (half << 6) + p_;
      float h = wx*xs[p*3] + wy*xs[p*3+1] + wz*xs[p*3+2];
      s += h; ss += h*h;
      convout[(size_t)(P0 + p)*128 + c] = (u16)(mono(f2bf(h)) ^ flip);
    }
    atomicAdd(&colsum[c], s);
    atomicAdd(&colss[c], ss);
    __syncthreads();
    if (tid < 16) {
      float gs = 0.f, gss = 0.f;
      #pragma unroll
      for (int q = 0; q < 8; ++q) { gs += colsum[tid*8+q]; gss += colss[tid*8+q]; }
      int b = P0 >> 11;
      atomicAdd(&gsum[(b*16 + tid)*2],   gs);
      atomicAdd(&gsum[(b*16 + tid)*2+1], gss);
    }
    return;
  }

  // ---------- knn path ----------
  const int wid = tid >> 6;
  const int lane = tid & 63;
  const int batch = blockIdx.x & 7;
  const int qib = (blockIdx.x >> 3) * 4 + wid;      // query within batch
  const int blk = (batch << 11) + qib;
  const float4* cb = c4 + (batch << 11);
  const float4 q = cb[qib];

  u32 key[32];
  #pragma unroll
  for (int s = 0; s < 32; ++s) {
    float4 c = cb[s*64 + lane];
    float inner = __fadd_rn(__fadd_rn(__fmul_rn(q.x,c.x), __fmul_rn(q.y,c.y)), __fmul_rn(q.z,c.z));
    float pd = __fsub_rn(__fsub_rn(__fmul_rn(2.0f, inner), q.w), c.w);
    u32 bits = __float_as_uint(pd);
    key[s] = (bits & 0x80000000u) ? ~bits : (bits | 0x80000000u);
  }

  // wave-max of non-self keys (self key is exactly 0x80000000; excluded by value)
  u32 Mh = 0;
  #pragma unroll
  for (int s = 0; s < 32; ++s) {
    u32 kk = key[s];
    if (kk != 0x80000000u && kk > Mh) Mh = kk;
  }
  #pragma unroll
  for (int m = 32; m; m >>= 1) {
    u32 o = __shfl_xor(Mh, m, 64);
    if (o > Mh) Mh = o;
  }

  // radix bisect with prefix skip (invariant incl. bit31; see R17 note)
  u32 T = 0;
  bool onpfx = ((Mh & 0x80000000u) == 0u);
  for (int bit = 30; bit >= 0; --bit) {
    if (onpfx && !((Mh >> bit) & 1u)) continue;
    u32 Tc = T | (1u << bit);
    int c = 0;
    #pragma unroll
    for (int s = 0; s < 32; ++s)
      c += __popcll(__ballot(key[s] >= Tc));
    if (c >= 80) { T = Tc; if (c <= 128) break; }
    else onpfx = false;
  }

  cand[wid][lane] = 0ull;
  cand[wid][lane + 64] = 0ull;
  asm volatile("s_waitcnt lgkmcnt(0)" ::: "memory");

  const u64 below = (lane == 0) ? 0ull : (~0ull >> (64 - lane));
  int base = 0;
  #pragma unroll
  for (int s = 0; s < 32; ++s) {
    u64 msk = __ballot(key[s] >= T);
    if (key[s] >= T) {
      int pos = base + (int)__popcll(msk & below);
      if (pos < 128)
        cand[wid][pos] = (((u64)key[s]) << 32) | (u32)(2047 - (s*64 + lane));
    }
    base += (int)__popcll(msk);
  }
  asm volatile("s_waitcnt lgkmcnt(0)" ::: "memory");

  u64 v0 = cand[wid][lane];
  u64 v1 = cand[wid][lane + 64];
  #pragma unroll
  for (int k2 = 2; k2 <= 128; k2 <<= 1) {
    #pragma unroll
    for (int j = k2 >> 1; j > 0; j >>= 1) {
      if (j == 64) {                                // cross-slot, in-lane
        u64 mx = v0 > v1 ? v0 : v1;
        u64 mn = v0 > v1 ? v1 : v0;
        v0 = mx; v1 = mn;
      } else {
        u64 p0 = __shfl_xor(v0, j, 64);
        u64 p1 = __shfl_xor(v1, j, 64);
        bool lowlane = ((lane & j) == 0);
        bool d0 = ((lane & k2) == 0);
        bool d1 = (((lane + 64) & k2) == 0);
        bool wm0 = (d0 == lowlane);
        bool wm1 = (d1 == lowlane);
        u64 mx0 = v0 > p0 ? v0 : p0, mn0 = v0 > p0 ? p0 : v0;
        u64 mx1 = v1 > p1 ? v1 : p1, mn1 = v1 > p1 ? p1 : v1;
        v0 = wm0 ? mx0 : mn0;
        v1 = wm1 ? mx1 : mn1;
      }
    }
  }

  idxp[(size_t)blk*80 + lane] = 2047 - (int)(u32)v0;
  if (lane < 16) idxp[(size_t)blk*80 + 64 + lane] = 2047 - (int)(u32)v1;
}

// ---------------- fused gather-max + GroupNorm + LeakyReLU + add-fb ----------------
__global__ __launch_bounds__(256) void k_gather(const u16* __restrict__ conv, int Ctot, int Ca,
    int CgShift, int NG, const float* __restrict__ gsum,
    const float* __restrict__ ga, const float* __restrict__ ba,
    const float* __restrict__ gb, const float* __restrict__ bb,
    const int* __restrict__ idxp, int k,
    u16* __restrict__ xcat, int outOff, int lppShift) {
  const int batch = blockIdx.x & 7;
  const int blkin = blockIdx.x >> 3;
  const int lgid = blkin * 256 + threadIdx.x;
  const int p_in = lgid >> lppShift;
  const int c8 = (lgid & ((1 << lppShift) - 1)) * 8;
  const int p = (batch << 11) + p_in;
  const int* irow = idxp + (size_t)p * 80;
  const u16* cb = conv + ((size_t)(batch << 11)) * Ctot + c8;

  const int gia = c8 >> CgShift;
  const int gib = (Ca + c8) >> CgShift;
  const float cnt = (float)(2048 << CgShift);
  float2 sa = *(const float2*)(gsum + (size_t)(batch*NG + gia)*2);
  float2 sb = *(const float2*)(gsum + (size_t)(batch*NG + gib)*2);
  float meanA = sa.x / cnt, rstdA = rsqrtf(sa.y / cnt - meanA*meanA + 1e-5f);
  float meanB = sb.x / cnt, rstdB = rsqrtf(sb.y / cnt - meanB*meanB + 1e-5f);

  float gav[8], bav[8], gbv[8], bbv[8];
  *(float4*)&gav[0] = *(const float4*)(ga + c8); *(float4*)&gav[4] = *(const float4*)(ga + c8 + 4);
  *(float4*)&bav[0] = *(const float4*)(ba + c8); *(float4*)&bav[4] = *(const float4*)(ba + c8 + 4);
  *(float4*)&gbv[0] = *(const float4*)(gb + c8); *(float4*)&gbv[4] = *(const float4*)(gb + c8 + 4);
  *(float4*)&bbv[0] = *(const float4*)(bb + c8); *(float4*)&bbv[4] = *(const float4*)(bb + c8 + 4);

  u16x8 fbv = *(const u16x8*)(conv + (size_t)p * Ctot + Ca + c8);

  u16x8 m8 = (u16x8)(u16)0;
  for (int j0 = 0; j0 < k; j0 += 4) {
    int4 mi4 = *(const int4*)(irow + j0);
    int mis[4] = {mi4.x, mi4.y, mi4.z, mi4.w};
    u16x8 rows[4];
    #pragma unroll
    for (int u = 0; u < 4; ++u)
      rows[u] = *(const u16x8*)(cb + (size_t)mis[u] * Ctot);
    #pragma unroll
    for (int u = 0; u < 4; ++u)
      m8 = __builtin_elementwise_max(m8, rows[u]);   // v_pk_max_u16
  }

  u16 ov[8];
  #pragma unroll
  for (int q = 0; q < 8; ++q) {
    u16 fA = (gav[q] < 0.f) ? (u16)0xFFFF : (u16)0;
    u16 fB = (gbv[q] < 0.f) ? (u16)0xFFFF : (u16)0;
    float xa = bf2f(unmono((u16)((u16)m8[q] ^ fA)));
    float ha = (xa - meanA) * rstdA * gav[q] + bav[q];
    ha = ha > 0.f ? ha : 0.2f * ha;
    float xb = bf2f(unmono((u16)((u16)fbv[q] ^ fB)));
    float hb = (xb - meanB) * rstdB * gbv[q] + bbv[q];
    hb = hb > 0.f ? hb : 0.2f * hb;
    ov[q] = f2bf(ha + hb);
  }
  *(u16x8*)(xcat + (size_t)p * 512 + outOff + c8) = *(u16x8*)ov;
}

// ---------------- GN apply + LeakyReLU (layer 5_2): bf16 in, f32 out ----------------
__global__ __launch_bounds__(256) void k_apply52(const u16* __restrict__ h2,
    float* __restrict__ outp, const float* __restrict__ gsum,
    const float* __restrict__ g, const float* __restrict__ b) {
  int gid = blockIdx.x * 256 + threadIdx.x;          // grid 4096 -> 8 elems/thread
  size_t e = (size_t)gid * 8;
  int row = (int)(e >> 9);                           // Ctot = 512
  int c = (int)e & 511;
  int grp = c >> 5;
  float2 s = *(const float2*)(gsum + (size_t)((row >> 11)*16 + grp)*2);
  const float cnt = 65536.f;
  float mean = s.x / cnt, rstd = rsqrtf(s.y / cnt - mean*mean + 1e-5f);
  u16x8 v = *(const u16x8*)(h2 + e);
  float gv[8], bv[8];
  *(float4*)&gv[0] = *(const float4*)(g + c); *(float4*)&gv[4] = *(const float4*)(g + c + 4);
  *(float4*)&bv[0] = *(const float4*)(b + c); *(float4*)&bv[4] = *(const float4*)(b + c + 4);
  float h[8];
  #pragma unroll
  for (int q = 0; q < 8; ++q) {
    float xv = bf2f((u16)v[q]);
    float o = (xv - mean) * rstd * gv[q] + bv[q];
    h[q] = o > 0.f ? o : 0.2f * o;
  }
  *(float4*)(outp + e)     = make_float4(h[0], h[1], h[2], h[3]);
  *(float4*)(outp + e + 4) = make_float4(h[4], h[5], h[6], h[7]);
}

// ---------------- bf16 MFMA GEMM + fused GN stats + mono' store (128x128 tile) ----------------
// TRANSA: previous layer's GN+LReLU applied inline during A staging, with the
// scale/bias computed ON THE FLY from gsA (layer-5_1 stats) + gA/bA (gamma/beta):
// each 8-ch staging chunk lies in exactly one 64-ch group -> one mean/rstd per chunk.
// Bit-identical to the old sc/bi-table path (same op order as k_sb51).
template<int OUTF32, int MONO, int TRANSA>
__global__ __launch_bounds__(256) void k_gemm(const u16* __restrict__ A, int lda,
    const u16* __restrict__ Bw, int K, void* __restrict__ outp, int ldc,
    int CgShift, int NG, float* __restrict__ gsum,
    const float* __restrict__ ga, const float* __restrict__ gb, int Ca,
    const float* __restrict__ gsA, const float* __restrict__ gA,
    const float* __restrict__ bA) {
  constexpr int BK = 64;
  __shared__ __align__(16) u16 As[128 * BK];
  __shared__ __align__(16) u16 Bs[128 * BK];
  __shared__ float colsum[128], colss[128];
  const int tid = threadIdx.x;
  const int wid = tid >> 6, lane = tid & 63;
  const int tileM = blockIdx.x * 128, tileN = blockIdx.y * 128;
  const int wm = wid >> 1, wn = wid & 1;
  const int lr = lane & 15, lk = (lane >> 4) * 8;
  const float* gsAb = TRANSA ? (gsA + (size_t)(tileM >> 11) * 32) : nullptr; // 16 grp * 2
  f32x4 acc[4][4] = {};
  for (int k0 = 0; k0 < K; k0 += BK) {
    __syncthreads();
    #pragma unroll
    for (int i = 0; i < 4; ++i) {
      int flat = i * 256 + tid;
      int row = flat >> 3, ck = flat & 7;
      if (TRANSA) {
        int cbase = k0 + ck * 8;
        uint4 v = *(const uint4*)(A + (size_t)(tileM + row) * lda + cbase);
        // one 64-ch group per 8-ch chunk (cbase % 8 == 0, 8 | 64)
        float2 st = *(const float2*)(gsAb + (cbase >> 6) * 2);
        float mean = st.x / 131072.f;
        float rstd = rsqrtf(st.y / 131072.f - mean*mean + 1e-5f);
        float4 g0 = *(const float4*)(gA + cbase);
        float4 g1 = *(const float4*)(gA + cbase + 4);
        float4 b0 = *(const float4*)(bA + cbase);
        float4 b1 = *(const float4*)(bA + cbase + 4);
        float gv8[8] = {g0.x,g0.y,g0.z,g0.w,g1.x,g1.y,g1.z,g1.w};
        float bv8[8] = {b0.x,b0.y,b0.z,b0.w,b1.x,b1.y,b1.z,b1.w};
        u32 vv[4] = {v.x, v.y, v.z, v.w};
        u32 ov[4];
        #pragma unroll
        for (int q2 = 0; q2 < 4; ++q2) {
          float Asc0 = rstd * gv8[q2*2];
          float Asc1 = rstd * gv8[q2*2+1];
          float Bbi0 = bv8[q2*2]   - mean * Asc0;
          float Bbi1 = bv8[q2*2+1] - mean * Asc1;
          float x0 = bf2f((u16)(vv[q2] & 0xFFFF));
          float x1 = bf2f((u16)(vv[q2] >> 16));
          float o0 = x0 * Asc0 + Bbi0;
          float o1 = x1 * Asc1 + Bbi1;
          o0 = o0 > 0.f ? o0 : 0.2f * o0;
          o1 = o1 > 0.f ? o1 : 0.2f * o1;
          ov[q2] = (u32)f2bf(o0) | (((u32)f2bf(o1)) << 16);
        }
        *(uint4*)((char*)As + flat * 16) = make_uint4(ov[0], ov[1], ov[2], ov[3]);
      } else {
        glds16(A + (size_t)(tileM + row) * lda + (k0 + ck * 8), (char*)As + flat * 16);
      }
    }
    #pragma unroll
    for (int i = 0; i < 4; ++i) {
      int flat = i * 256 + tid;
      int row = flat >> 3, ck = flat & 7;
      glds16(Bw + (size_t)(tileN + row) * K + (k0 + ck * 8), (char*)Bs + flat * 16);
    }
    __syncthreads();
    #pragma unroll
    for (int ks = 0; ks < 2; ++ks) {
      bf16x8 af[4], bfr[4];
      #pragma unroll
      for (int i = 0; i < 4; ++i)
        af[i] = *(const bf16x8*)&As[(wm*64 + i*16 + lr) * BK + ks*32 + lk];
      #pragma unroll
      for (int j = 0; j < 4; ++j)
        bfr[j] = *(const bf16x8*)&Bs[(wn*64 + j*16 + lr) * BK + ks*32 + lk];
      #pragma unroll
      for (int i = 0; i < 4; ++i)
        #pragma unroll
        for (int j = 0; j < 4; ++j)
          acc[i][j] = __builtin_amdgcn_mfma_f32_16x16x32_bf16(af[i], bfr[j], acc[i][j], 0, 0, 0);
    }
  }
  const int orow0 = tileM + wm*64 + ((lane >> 4) * 4);
  const int ocol0 = tileN + wn*64 + lr;

  u16 flip[4] = {0,0,0,0};
  if (MONO) {
    #pragma unroll
    for (int j = 0; j < 4; ++j) {
      int colg = ocol0 + j*16;
      float gm = (colg < Ca) ? ga[colg] : gb[colg - Ca];
      flip[j] = (gm < 0.f) ? (u16)0xFFFF : (u16)0;
    }
  }

  float csum[4] = {0.f,0.f,0.f,0.f}, css[4] = {0.f,0.f,0.f,0.f};
  #pragma unroll
  for (int i = 0; i < 4; ++i)
    #pragma unroll
    for (int j = 0; j < 4; ++j)
      #pragma unroll
      for (int r = 0; r < 4; ++r) {
        int row = orow0 + i*16 + r;
        int col = ocol0 + j*16;
        float v = acc[i][j][r];
        csum[j] += v; css[j] += v*v;
        if (OUTF32) ((float*)outp)[(size_t)row * ldc + col] = v;
        else {
          u16 st = f2bf(v);
          if (MONO) st = (u16)(mono(st) ^ flip[j]);
          ((u16*)outp)[(size_t)row * ldc + col] = st;
        }
      }

  #pragma unroll
  for (int mask = 16; mask <= 32; mask <<= 1)
    #pragma unroll
    for (int j = 0; j < 4; ++j) {
      csum[j] += __shfl_xor(csum[j], mask, 64);
      css[j]  += __shfl_xor(css[j],  mask, 64);
    }
  if (tid < 128) { colsum[tid] = 0.f; colss[tid] = 0.f; }
  __syncthreads();
  if ((lane >> 4) == 0) {
    #pragma unroll
    for (int j = 0; j < 4; ++j) {
      int col = wn*64 + j*16 + lr;
      atomicAdd(&colsum[col], csum[j]);
      atomicAdd(&colss[col],  css[j]);
    }
  }
  __syncthreads();
  const int NGtile = 128 >> CgShift;
  if (tid < NGtile) {
    float s = 0.f, ss = 0.f;
    const int Cg = 1 << CgShift;
    for (int c0 = tid << CgShift; c0 < (tid << CgShift) + Cg; ++c0) { s += colsum[c0]; ss += colss[c0]; }
    int b = tileM >> 11;
    int gidx = (tileN >> CgShift) + tid;
    atomicAdd(&gsum[(size_t)(b*NG + gidx)*2],   s);
    atomicAdd(&gsum[(size_t)(b*NG + gidx)*2+1], ss);
  }
}

// ---------------- 64x128-tile GEMM — small L2/L3 gemms (full-chip coverage) ----------------
template<int MONO>
__global__ __launch_bounds__(256, 6) void k_gemm64(const u16* __restrict__ A, int lda,
    const u16* __restrict__ Bw, int K, u16* __restrict__ outp, int ldc,
    int CgShift, int NG, float* __restrict__ gsum,
    const float* __restrict__ ga, const float* __restrict__ gb, int Ca) {
  constexpr int BK = 64;
  __shared__ __align__(16) u16 As[64 * BK];         // 8 KB
  __shared__ __align__(16) u16 Bs[128 * BK];        // 16 KB
  __shared__ float colsum[128], colss[128];
  const int tid = threadIdx.x;
  const int wid = tid >> 6, lane = tid & 63;
  const int tileM = blockIdx.x * 64, tileN = blockIdx.y * 128;
  const int wn = wid;                               // 4 waves: cols wn*32..wn*32+31
  const int lr = lane & 15, lk = (lane >> 4) * 8;

  f32x4 acc[4][2] = {};
  for (int k0 = 0; k0 < K; k0 += BK) {
    __syncthreads();
    #pragma unroll
    for (int i = 0; i < 2; ++i) {                   // A tile: 64x64 u16 = 512 chunks
      int flat = i * 256 + tid;
      int row = flat >> 3, ck = flat & 7;
      glds16(A + (size_t)(tileM + row) * lda + (k0 + ck * 8), (char*)As + flat * 16);
    }
    #pragma unroll
    for (int i = 0; i < 4; ++i) {                   // B tile: 128x64 u16 = 1024 chunks
      int flat = i * 256 + tid;
      int row = flat >> 3, ck = flat & 7;
      glds16(Bw + (size_t)(tileN + row) * K + (k0 + ck * 8), (char*)Bs + flat * 16);
    }
    __syncthreads();
    #pragma unroll
    for (int ks = 0; ks < 2; ++ks) {
      bf16x8 af[4], bfr[2];
      #pragma unroll
      for (int i = 0; i < 4; ++i)
        af[i] = *(const bf16x8*)&As[(i*16 + lr) * BK + ks*32 + lk];
      #pragma unroll
      for (int j = 0; j < 2; ++j)
        bfr[j] = *(const bf16x8*)&Bs[(wn*32 + j*16 + lr) * BK + ks*32 + lk];
      #pragma unroll
      for (int i = 0; i < 4; ++i)
        #pragma unroll
        for (int j = 0; j < 2; ++j)
          acc[i][j] = __builtin_amdgcn_mfma_f32_16x16x32_bf16(af[i], bfr[j], acc[i][j], 0, 0, 0);
    }
  }

  const int orow0 = tileM + ((lane >> 4) * 4);
  const int ocol0 = tileN + wn*32 + lr;

  u16 flip[2] = {0,0};
  if (MONO) {
    #pragma unroll
    for (int j = 0; j < 2; ++j) {
      int colg = ocol0 + j*16;
      float gm = (colg < Ca) ? ga[colg] : gb[colg - Ca];
      flip[j] = (gm < 0.f) ? (u16)0xFFFF : (u16)0;
    }
  }

  float csum[2] = {0.f,0.f}, css[2] = {0.f,0.f};
  #pragma unroll
  for (int i = 0; i < 4; ++i)
    #pragma unroll
    for (int j = 0; j < 2; ++j)
      #pragma unroll
      for (int r = 0; r < 4; ++r) {
        int row = orow0 + i*16 + r;
        int col = ocol0 + j*16;
        float v = acc[i][j][r];
        csum[j] += v; css[j] += v*v;
        u16 st = f2bf(v);
        if (MONO) st = (u16)(mono(st) ^ flip[j]);
        outp[(size_t)row * ldc + col] = st;
      }

  #pragma unroll
  for (int mask = 16; mask <= 32; mask <<= 1)
    #pragma unroll
    for (int j = 0; j < 2; ++j) {
      csum[j] += __shfl_xor(csum[j], mask, 64);
      css[j]  += __shfl_xor(css[j],  mask, 64);
    }
  if (tid < 128) { colsum[tid] = 0.f; colss[tid] = 0.f; }
  __syncthreads();
  if ((lane >> 4) == 0) {
    #pragma unroll
    for (int j = 0; j < 2; ++j) {
      int col = wn*32 + j*16 + lr;
      atomicAdd(&colsum[col], csum[j]);
      atomicAdd(&colss[col],  css[j]);
    }
  }
  __syncthreads();
  const int NGtile = 128 >> CgShift;
  if (tid < NGtile) {
    float s = 0.f, ss = 0.f;
    const int Cg = 1 << CgShift;
    for (int c0 = tid << CgShift; c0 < (tid << CgShift) + Cg; ++c0) { s += colsum[c0]; ss += colss[c0]; }
    int b = tileM >> 11;
    int gidx = (tileN >> CgShift) + tid;
    atomicAdd(&gsum[(size_t)(b*NG + gidx)*2],   s);
    atomicAdd(&gsum[(size_t)(b*NG + gidx)*2+1], ss);
  }
}

// ---------------- launch ----------------
extern "C" void kernel_launch(void* const* d_in, const int* in_sizes, int n_in,
                              void* d_out, int out_size, void* d_ws, size_t ws_size,
                              hipStream_t stream) {
  const float* x   = (const float*)d_in[0];
  const float* w1a = (const float*)d_in[1];
  const float* g1a = (const float*)d_in[2];
  const float* b1a = (const float*)d_in[3];
  const float* w1b = (const float*)d_in[4];
  const float* g1b = (const float*)d_in[5];
  const float* b1b = (const float*)d_in[6];
  const float* w2a = (const float*)d_in[7];
  const float* g2a = (const float*)d_in[8];
  const float* b2a = (const float*)d_in[9];
  const float* w2b = (const float*)d_in[10];
  const float* g2b = (const float*)d_in[11];
  const float* b2b = (const float*)d_in[12];
  const float* w3a = (const float*)d_in[13];
  const float* g3a = (const float*)d_in[14];
  const float* b3a = (const float*)d_in[15];
  const float* w3b = (const float*)d_in[16];
  const float* g3b = (const float*)d_in[17];
  const float* b3b = (const float*)d_in[18];
  const float* w4a = (const float*)d_in[19];
  const float* g4a = (const float*)d_in[20];
  const float* b4a = (const float*)d_in[21];
  const float* w4b = (const float*)d_in[22];
  const float* g4b = (const float*)d_in[23];
  const float* b4b = (const float*)d_in[24];
  const float* w51 = (const float*)d_in[25];
  const float* g51 = (const float*)d_in[26];
  const float* b51 = (const float*)d_in[27];
  const float* w52 = (const float*)d_in[28];
  const float* g52 = (const float*)d_in[29];
  const float* b52 = (const float*)d_in[30];

  char* ws = (char*)d_ws;
  int*    idxp   = (int*)   (ws + 0);               // 5,242,880 (dead after L4 gather)
  float4* c4     = (float4*)(ws + 5242880);         // 262,144
  u16*    wbf    = (u16*)   (ws + 5505024);         // 2,277,376
  float*  gsum   = (float*) (ws + 7782400);         // 8,192
  u16*    convAB = (u16*)   (ws + 7790592);         // 16,777,216 (dead after L4 gather)
  u16*    h1     = (u16*)   (ws + 24567808);        // 33,554,432
  u16*    xcat   = (u16*)   (ws + 58122240);        // 16,777,216
  // after L4 gather: h2 (bf16 5_2 out) reuses the convAB region
  u16*    h2     = (u16*)   (ws + 7790592);         // 16,777,216 (16384*512*2)
  u16* wc2 = wbf, *wc3 = wbf + 8192, *wc4 = wbf + 24576;
  u16* w51b = wbf + 90112, *w52b = wbf + 614400;
  float* outf = (float*)d_out;
  float* gsL1 = gsum;        float* gsL2 = gsum + 256;  float* gsL3 = gsum + 512;
  float* gsL4 = gsum + 768;  float* gs51 = gsum + 1280; float* gs52 = gsum + 1536;

  k_pack_all<<<4448, 256, 0, stream>>>(x, c4, gsum, w2a, w2b, w3a, w3b, w4a, w4b,
                                       w51, w52, wbf);

  // knn (4096 blocks) + layer-1 conv (128 blocks) fused
  k_knn_conv1<<<4224, 256, 0, stream>>>(c4, idxp, x, w1a, w1b, g1a, g1b, convAB, gsL1);

  // layer 1 gather (+GN)
  k_gather<<<512, 256, 0, stream>>>(convAB, 128, 64, 3, 16, gsL1,
                                    g1a, b1a, g1b, b1b, idxp, 20, xcat, 0, 3);

  // layer 2 (small gemm: 64-tile, 256 blocks = full chip)
  k_gemm64<1><<<dim3(256,1), 256, 0, stream>>>(xcat + 0, 512, wc2, 64, convAB, 128,
                                               3, 16, gsL2, g2a, g2b, 64);
  k_gather<<<512, 256, 0, stream>>>(convAB, 128, 64, 3, 16, gsL2,
                                    g2a, b2a, g2b, b2b, idxp, 40, xcat, 64, 3);

  // layer 3 (small gemm: 64-tile, 512 blocks)
  k_gemm64<1><<<dim3(256,2), 256, 0, stream>>>(xcat + 64, 512, wc3, 64, convAB, 256,
                                               4, 16, gsL3, g3a, g3b, 128);
  k_gather<<<1024, 256, 0, stream>>>(convAB, 256, 128, 4, 16, gsL3,
                                     g3a, b3a, g3b, b3b, idxp, 60, xcat, 128, 4);

  // layer 4 (128^2 tile — best measured for the big gemms)
  k_gemm<0,1,0><<<dim3(128,4), 256, 0, stream>>>(xcat + 128, 512, wc4, 128, convAB, 512,
                                                 4, 32, gsL4, g4a, g4b, 256,
                                                 nullptr, nullptr, nullptr);
  k_gather<<<2048, 256, 0, stream>>>(convAB, 512, 256, 4, 32, gsL4,
                                     g4a, b4a, g4b, b4b, idxp, 80, xcat, 256, 5);

  // layer 5_1 (512->1024): GEMM(raw out)+stats
  k_gemm<0,0,0><<<dim3(128,8), 256, 0, stream>>>(xcat, 512, w51b, 512, h1, 1024,
                                                 6, 16, gs51, g51, g51, 1024,
                                                 nullptr, nullptr, nullptr);

  // layer 5_2 (1024->512): GEMM(bf16 out -> h2)+stats, 5_1's GN+LReLU computed inline
  // from gs51/g51/b51 during A staging (k_sb51 eliminated)
  k_gemm<0,0,1><<<dim3(128,4), 256, 0, stream>>>(h1, 1024, w52b, 1024, h2, 512,
                                                 5, 16, gs52, g52, g52, 512,
                                                 gs51, g51, b51);
  // final GN apply: bf16 h2 -> f32 d_out
  k_apply52<<<4096, 256, 0, stream>>>(h2, outf, gs52, g52, b52);
}